// Round 1
// baseline (1258.278 us; speedup 1.0000x reference)
//
#include <hip/hip_runtime.h>
#include <hip/hip_bf16.h>

#define DEPTH 4
#define HEADS 16
#define DIMH  64
#define DIM   1024
#define MLPD  4096
#define NTOK  1024
#define BATCH 4
#define ROWS  (BATCH*NTOK)      // 4096
#define SCALE 0.125f            // 64^-0.5

typedef float f32x4 __attribute__((ext_vector_type(4)));
typedef short s16x8 __attribute__((ext_vector_type(8)));

#define MFMA(a,b,c) __builtin_amdgcn_mfma_f32_16x16x32_bf16((a),(b),(c),0,0,0)

__device__ __forceinline__ unsigned short f2bf(float f){
  union{ __hip_bfloat16 h; unsigned short u; } x; x.h = __float2bfloat16(f); return x.u;
}
__device__ __forceinline__ float bf2f(unsigned short u){
  return __uint_as_float(((unsigned)u)<<16);
}

__device__ __forceinline__ void async16(const void* g, void* l){
  __builtin_amdgcn_global_load_lds(
      (const __attribute__((address_space(1))) void*)g,
      (__attribute__((address_space(3))) void*)l, 16, 0, 0);
}

// ---------------------------------------------------------------------------
// Weight convert+transpose: src fp32 [D][K][N] -> dst bf16(ushort) [D][N][K]
// grid: (N/64, K/64, D), block 256
// ---------------------------------------------------------------------------
__global__ __launch_bounds__(256) void wt_kernel(const float* __restrict__ src,
    unsigned short* __restrict__ dst, int K, int N)
{
  __shared__ float t[64][65];
  int n0 = blockIdx.x*64, k0 = blockIdx.y*64;
  src += (size_t)blockIdx.z*K*N;
  dst += (size_t)blockIdx.z*N*K;
  int tid = threadIdx.x;
  int r = tid>>4, c4 = (tid&15)*4;
#pragma unroll
  for (int p=0;p<4;p++){
    int row = r + p*16;
    float4 v = *(const float4*)(src + (size_t)(k0+row)*N + n0 + c4);
    t[c4+0][row]=v.x; t[c4+1][row]=v.y; t[c4+2][row]=v.z; t[c4+3][row]=v.w;
  }
  __syncthreads();
  int rn = tid>>2, ch = tid&3;
  unsigned short o[16];
#pragma unroll
  for (int i=0;i<16;i++) o[i] = f2bf(t[rn][ch*16+i]);
  uint4* d = (uint4*)(dst + (size_t)(n0+rn)*K + k0 + ch*16);
  d[0] = ((uint4*)o)[0]; d[1] = ((uint4*)o)[1];
}

// ---------------------------------------------------------------------------
// LayerNorm fp32 -> bf16. One wave per row (1024 cols). block 256 = 4 rows.
// ---------------------------------------------------------------------------
__global__ __launch_bounds__(256) void ln_kernel(const float* __restrict__ x,
    const float* __restrict__ g, const float* __restrict__ b,
    unsigned short* __restrict__ h)
{
  int row  = blockIdx.x*4 + (threadIdx.x>>6);
  int lane = threadIdx.x & 63;
  const float* xr = x + (size_t)row*DIM;
  float4 v[4]; float s=0.f, ss=0.f;
#pragma unroll
  for (int c=0;c<4;c++){
    v[c] = *(const float4*)(xr + c*256 + lane*4);
    s  += v[c].x+v[c].y+v[c].z+v[c].w;
    ss += v[c].x*v[c].x+v[c].y*v[c].y+v[c].z*v[c].z+v[c].w*v[c].w;
  }
#pragma unroll
  for (int o=1;o<64;o<<=1){ s += __shfl_xor(s,o); ss += __shfl_xor(ss,o); }
  float mu  = s*(1.f/1024.f);
  float var = ss*(1.f/1024.f) - mu*mu;
  float rstd = rsqrtf(var + 1e-5f);
#pragma unroll
  for (int c=0;c<4;c++){
    float4 gg = *(const float4*)(g + c*256 + lane*4);
    float4 bb = *(const float4*)(b + c*256 + lane*4);
    ushort4 o;
    o.x = f2bf((v[c].x-mu)*rstd*gg.x + bb.x);
    o.y = f2bf((v[c].y-mu)*rstd*gg.y + bb.y);
    o.z = f2bf((v[c].z-mu)*rstd*gg.z + bb.z);
    o.w = f2bf((v[c].w-mu)*rstd*gg.w + bb.w);
    *(ushort4*)(h + (size_t)row*DIM + c*256 + lane*4) = o;
  }
}

// ---------------------------------------------------------------------------
// V transpose: qkv bf16 [B*N][3072] (v part cols 2048..3071, per-head 64)
//   -> vT [B*H*64][N].  grid (N/64, B*H), block 256.
// ---------------------------------------------------------------------------
__global__ __launch_bounds__(256) void vtrans_kernel(
    const unsigned short* __restrict__ qkv, unsigned short* __restrict__ vT)
{
  __shared__ float t[64][65];
  int n0 = blockIdx.x*64;
  int bh = blockIdx.y; int b = bh>>4, hh = bh&15;
  int tid = threadIdx.x;
  int r = tid>>4, c4 = (tid&15)*4;
#pragma unroll
  for (int p=0;p<4;p++){
    int row = r + p*16;   // token index within tile
    ushort4 u = *(const ushort4*)(qkv + (size_t)(b*NTOK + n0 + row)*3072 + 2048 + hh*64 + c4);
    t[c4+0][row]=bf2f(u.x); t[c4+1][row]=bf2f(u.y); t[c4+2][row]=bf2f(u.z); t[c4+3][row]=bf2f(u.w);
  }
  __syncthreads();
  int rn = tid>>2, ch = tid&3;   // rn = d index
  unsigned short o[16];
#pragma unroll
  for (int i=0;i<16;i++) o[i] = f2bf(t[rn][ch*16+i]);
  uint4* d = (uint4*)(vT + (size_t)(bh*64 + rn)*NTOK + n0 + ch*16);
  d[0] = ((uint4*)o)[0]; d[1] = ((uint4*)o)[1];
}

// ---------------------------------------------------------------------------
// GEMM: C[M][N] = A[M][K](bf16) * Bt[N][K](bf16)^T, m97 structure:
// 128xBN tile, BK=64, 256 threads (2x2 waves), global_load_lds w=16,
// XOR chunk swizzle (pre-swizzled source), XCD-swizzled block id.
// EPI 0: bf16 store. EPI 1: fp32 store of acc+res+bias. EPI 2: bf16 gelu(acc+bias).
// ---------------------------------------------------------------------------
template<int BN, int EPI>
__global__ __launch_bounds__(256) void gemm_kernel(
    const unsigned short* __restrict__ A,
    const unsigned short* __restrict__ Bt,
    unsigned short* __restrict__ outb,
    float* __restrict__ outf,
    const float* __restrict__ res,
    const float* __restrict__ bias,
    int M, int N, int K, int ldout)
{
  constexpr int BM=128, BK=64;
  constexpr int NT = BN/32;                 // n-frags per wave (wave tile = 64 x BN/2)
  __shared__ unsigned short As[BM*BK];
  __shared__ unsigned short Bs[BN*BK];
  int tid = threadIdx.x, lane = tid&63, w = tid>>6;
  int wm = w&1, wn = w>>1;

  int gn  = N/BN;
  int nwg = (M/BM)*gn;
  int bid = blockIdx.x;
  int id  = (nwg%8==0) ? ((bid&7)*(nwg>>3) + (bid>>3)) : bid;
  int m0 = (id/gn)*BM, n0 = (id%gn)*BN;

  f32x4 acc[4][NT] = {};

  for (int k0=0; k0<K; k0+=BK){
    __syncthreads();
#pragma unroll
    for (int i=0;i<4;i++){                  // stage A: 4 x 1KB per wave
      int off = w*4096 + i*1024 + lane*16;
      int row = off>>7, p = (off&127)>>4;
      async16(A + (size_t)(m0+row)*K + k0 + ((p^(row&7))<<3),
              (char*)As + w*4096 + i*1024);
    }
#pragma unroll
    for (int i=0;i<NT;i++){                 // stage B: NT x 1KB per wave
      int off = w*(BN*32) + i*1024 + lane*16;   // BN*BK*2/4 bytes per wave
      int row = off>>7, p = (off&127)>>4;
      async16(Bt + (size_t)(n0+row)*K + k0 + ((p^(row&7))<<3),
              (char*)Bs + w*(BN*32) + i*1024);
    }
    __syncthreads();
#pragma unroll
    for (int ks=0;ks<2;ks++){
      s16x8 a[4], bfr[NT];
#pragma unroll
      for (int mt=0;mt<4;mt++){
        int row = wm*64 + mt*16 + (lane&15);
        int c = (ks*4 + (lane>>4)) ^ (row&7);
        a[mt] = *(const s16x8*)((const char*)As + row*128 + c*16);
      }
#pragma unroll
      for (int nt=0;nt<NT;nt++){
        int row = wn*(BN/2) + nt*16 + (lane&15);
        int c = (ks*4 + (lane>>4)) ^ (row&7);
        bfr[nt] = *(const s16x8*)((const char*)Bs + row*128 + c*16);
      }
#pragma unroll
      for (int mt=0;mt<4;mt++)
#pragma unroll
        for (int nt=0;nt<NT;nt++)
          acc[mt][nt] = MFMA(a[mt], bfr[nt], acc[mt][nt]);
    }
  }

#pragma unroll
  for (int mt=0;mt<4;mt++)
#pragma unroll
    for (int nt=0;nt<NT;nt++)
#pragma unroll
      for (int r=0;r<4;r++){
        int row = m0 + wm*64 + mt*16 + ((lane>>4)<<2) + r;
        int col = n0 + wn*(BN/2) + nt*16 + (lane&15);
        float v = acc[mt][nt][r];
        if (EPI==0){
          outb[(size_t)row*ldout + col] = f2bf(v);
        } else if (EPI==1){
          float t = v + res[(size_t)row*ldout + col] + bias[col];
          outf[(size_t)row*ldout + col] = t;
        } else {
          float t = v + bias[col];
          t = 0.5f*t*(1.f + erff(t*0.70710678118f));
          outb[(size_t)row*ldout + col] = f2bf(t);
        }
      }
}

// ---------------------------------------------------------------------------
// Flash attention. grid (N/64, B*H), block 256 (4 waves x 16 q-rows).
// K,V chunk (64) staged in swizzled LDS via global_load_lds; S = Q K^T via
// MFMA; online softmax (16-lane shfl reduce); P bounced via per-wave LDS.
// ---------------------------------------------------------------------------
__global__ __launch_bounds__(256) void attn_kernel(
    const unsigned short* __restrict__ qkv,   // [B*N][3072]
    const unsigned short* __restrict__ vT,    // [B*H*64][N]
    const int* __restrict__ mnp, const int* __restrict__ mbert,
    unsigned short* __restrict__ outb)        // [B*N][1024]
{
  __shared__ unsigned short Ks[64*64];
  __shared__ unsigned short Vs[64*64];
  __shared__ unsigned short Pb[4][16*64];
  __shared__ float fm[NTOK];
  int qt = blockIdx.x, bh = blockIdx.y;
  int b = bh>>4, hh = bh&15;
  int tid = threadIdx.x, lane = tid&63, w = tid>>6;

  for (int j = tid; j < NTOK; j += 256)
    fm[j] = (mnp[b*NTOK+j]==0 || mbert[b*NTOK+j]==1) ? 1.f : 0.f;

  int iA = qt*64 + w*16 + (lane&15);
  s16x8 aq[2];
#pragma unroll
  for (int ks=0;ks<2;ks++)
    aq[ks] = *(const s16x8*)(qkv + (size_t)(b*NTOK+iA)*3072 + hh*64 + ks*32 + ((lane>>4)<<3));

  bool rowm[4]; float mreg[4], lsum[4]; f32x4 o[4];
#pragma unroll
  for (int r=0;r<4;r++){
    int i = qt*64 + w*16 + ((lane>>4)<<2) + r;
    rowm[r] = (mnp[b*NTOK+i]==0);
    mreg[r] = -1e30f; lsum[r] = 0.f;
    o[r] = f32x4{0.f,0.f,0.f,0.f};
  }

  for (int kc=0; kc<16; kc++){
    int j0 = kc*64;
    __syncthreads();
#pragma unroll
    for (int i=0;i<2;i++){
      int off = w*2048 + i*1024 + lane*16;
      int row = off>>7, p = (off&127)>>4;
      async16(qkv + (size_t)(b*NTOK + j0 + row)*3072 + 1024 + hh*64 + ((p^(row&7))<<3),
              (char*)Ks + w*2048 + i*1024);
      async16(vT + (size_t)(bh*64 + row)*NTOK + j0 + ((p^(row&7))<<3),
              (char*)Vs + w*2048 + i*1024);
    }
    __syncthreads();

    f32x4 sc[4];
#pragma unroll
    for (int jt=0;jt<4;jt++){
      sc[jt] = f32x4{0.f,0.f,0.f,0.f};
#pragma unroll
      for (int ks=0;ks<2;ks++){
        int row = jt*16 + (lane&15);
        int c = (ks*4 + (lane>>4)) ^ (row&7);
        s16x8 bk = *(const s16x8*)((const char*)Ks + row*128 + c*16);
        sc[jt] = MFMA(aq[ks], bk, sc[jt]);
      }
    }
#pragma unroll
    for (int jt=0;jt<4;jt++){
      float f = fm[j0 + jt*16 + (lane&15)];
#pragma unroll
      for (int r=0;r<4;r++){
        float s = sc[jt][r]*SCALE;
        sc[jt][r] = (f!=0.f || rowm[r]) ? -1000.f : s;
      }
    }
#pragma unroll
    for (int r=0;r<4;r++){
      float mx = fmaxf(fmaxf(sc[0][r],sc[1][r]), fmaxf(sc[2][r],sc[3][r]));
#pragma unroll
      for (int ofs=8;ofs>=1;ofs>>=1) mx = fmaxf(mx, __shfl_xor(mx, ofs));
      float mnew  = fmaxf(mreg[r], mx);
      float alpha = __expf(mreg[r]-mnew);
      mreg[r] = mnew;
      float rs = 0.f;
#pragma unroll
      for (int jt=0;jt<4;jt++){ float p = __expf(sc[jt][r]-mnew); sc[jt][r]=p; rs+=p; }
#pragma unroll
      for (int ofs=8;ofs>=1;ofs>>=1) rs += __shfl_xor(rs, ofs);
      lsum[r] = lsum[r]*alpha + rs;
#pragma unroll
      for (int nt=0;nt<4;nt++) o[nt][r] *= alpha;
    }
#pragma unroll
    for (int jt=0;jt<4;jt++)
#pragma unroll
      for (int r=0;r<4;r++){
        int ir = ((lane>>4)<<2)+r, jc = jt*16+(lane&15);
        int byteoff = ir*128 + ((((jc>>3))^(ir&7))<<4) + ((jc&7)<<1);
        *((unsigned short*)((char*)Pb[w] + byteoff)) = f2bf(sc[jt][r]);
      }
#pragma unroll
    for (int ks=0;ks<2;ks++){
      int rowp = lane&15;
      int cp = (ks*4 + (lane>>4)) ^ (rowp&7);
      s16x8 ap = *(const s16x8*)((const char*)Pb[w] + rowp*128 + cp*16);
#pragma unroll
      for (int nt=0;nt<4;nt++){
        int d = nt*16 + (lane&15);
        int c = (ks*4 + (lane>>4)) ^ (d&7);
        s16x8 bv = *(const s16x8*)((const char*)Vs + d*128 + c*16);
        o[nt] = MFMA(ap, bv, o[nt]);
      }
    }
  }

#pragma unroll
  for (int r=0;r<4;r++){
    float inv = 1.f/lsum[r];
    int i = qt*64 + w*16 + ((lane>>4)<<2) + r;
#pragma unroll
    for (int nt=0;nt<4;nt++){
      int d = nt*16 + (lane&15);
      outb[(size_t)(b*NTOK+i)*DIM + hh*64 + d] = f2bf(o[nt][r]*inv);
    }
  }
}

// ---------------------------------------------------------------------------
extern "C" void kernel_launch(void* const* d_in, const int* in_sizes, int n_in,
                              void* d_out, int out_size, void* d_ws, size_t ws_size,
                              hipStream_t stream)
{
  const float* xin0 = (const float*)d_in[0];
  const float* Wqkv = (const float*)d_in[1];
  const float* Wout = (const float*)d_in[2];
  const float* bout = (const float*)d_in[3];
  const float* ln1g = (const float*)d_in[4];
  const float* ln1b = (const float*)d_in[5];
  const float* W1   = (const float*)d_in[6];
  const float* b1   = (const float*)d_in[7];
  const float* W2   = (const float*)d_in[8];
  const float* b2   = (const float*)d_in[9];
  const float* ln2g = (const float*)d_in[10];
  const float* ln2b = (const float*)d_in[11];
  const int*   mnp  = (const int*)d_in[12];
  const int*   mbt  = (const int*)d_in[13];
  float* out = (float*)d_out;

  // workspace carve (bytes): total ~192 MiB
  unsigned short* Wqkv_t = (unsigned short*)d_ws;            // 4*3072*1024
  unsigned short* Wout_t = Wqkv_t + (size_t)4*3072*1024;     // 4*1024*1024
  unsigned short* W1_t   = Wout_t + (size_t)4*1024*1024;     // 4*4096*1024
  unsigned short* W2_t   = W1_t   + (size_t)4*4096*1024;     // 4*1024*4096
  float*          x      = (float*)(W2_t + (size_t)4*1024*4096);
  unsigned short* hbuf   = (unsigned short*)(x + (size_t)ROWS*DIM);
  unsigned short* qkvb   = hbuf  + (size_t)ROWS*DIM;
  unsigned short* vTb    = qkvb  + (size_t)ROWS*3072;
  unsigned short* attnb  = vTb   + (size_t)ROWS*DIM;
  unsigned short* gbuf   = attnb + (size_t)ROWS*DIM;

  wt_kernel<<<dim3(3072/64,1024/64,4),256,0,stream>>>(Wqkv, Wqkv_t, 1024, 3072);
  wt_kernel<<<dim3(1024/64,1024/64,4),256,0,stream>>>(Wout, Wout_t, 1024, 1024);
  wt_kernel<<<dim3(4096/64,1024/64,4),256,0,stream>>>(W1,   W1_t,   1024, 4096);
  wt_kernel<<<dim3(1024/64,4096/64,4),256,0,stream>>>(W2,   W2_t,   4096, 1024);

  for (int l=0;l<4;l++){
    const float* xres = (l==0) ? xin0 : x;
    ln_kernel<<<1024,256,0,stream>>>(xres, ln1g+l*DIM, ln1b+l*DIM, hbuf);
    gemm_kernel<128,0><<<768,256,0,stream>>>(hbuf, Wqkv_t + (size_t)l*3072*1024,
        qkvb, nullptr, nullptr, nullptr, ROWS, 3072, 1024, 3072);
    vtrans_kernel<<<dim3(16,64),256,0,stream>>>(qkvb, vTb);
    attn_kernel<<<dim3(16,64),256,0,stream>>>(qkvb, vTb, mnp, mbt, attnb);
    gemm_kernel<64,1><<<512,256,0,stream>>>(attnb, Wout_t + (size_t)l*1024*1024,
        nullptr, x, xres, bout+l*DIM, ROWS, 1024, 1024, 1024);
    ln_kernel<<<1024,256,0,stream>>>(x, ln2g+l*DIM, ln2b+l*DIM, hbuf);
    gemm_kernel<128,2><<<1024,256,0,stream>>>(hbuf, W1_t + (size_t)l*4096*1024,
        gbuf, nullptr, nullptr, b1+l*MLPD, ROWS, 4096, 1024, 4096);
    float* xo = (l==3) ? out : x;
    gemm_kernel<64,1><<<512,256,0,stream>>>(gbuf, W2_t + (size_t)l*1024*4096,
        nullptr, xo, x, b2+l*DIM, ROWS, 1024, 4096, 1024);
  }
}

// Round 2
// 1216.858 us; speedup vs baseline: 1.0340x; 1.0340x over previous
//
#include <hip/hip_runtime.h>
#include <hip/hip_bf16.h>

#define DEPTH 4
#define HEADS 16
#define DIMH  64
#define DIM   1024
#define MLPD  4096
#define NTOK  1024
#define BATCH 4
#define ROWS  (BATCH*NTOK)      // 4096
#define SCALE 0.125f            // 64^-0.5

typedef float f32x4 __attribute__((ext_vector_type(4)));
typedef short s16x8 __attribute__((ext_vector_type(8)));

#define MFMA(a,b,c) __builtin_amdgcn_mfma_f32_16x16x32_bf16((a),(b),(c),0,0,0)

__device__ __forceinline__ unsigned short f2bf(float f){
  union{ __hip_bfloat16 h; unsigned short u; } x; x.h = __float2bfloat16(f); return x.u;
}
__device__ __forceinline__ float bf2f(unsigned short u){
  return __uint_as_float(((unsigned)u)<<16);
}

__device__ __forceinline__ void async16(const void* g, void* l){
  __builtin_amdgcn_global_load_lds(
      (const __attribute__((address_space(1))) void*)g,
      (__attribute__((address_space(3))) void*)l, 16, 0, 0);
}

// ---------------------------------------------------------------------------
// Weight convert+transpose: src fp32 [D][K][N] -> dst bf16(ushort) [D][N][K]
// ---------------------------------------------------------------------------
__global__ __launch_bounds__(256) void wt_kernel(const float* __restrict__ src,
    unsigned short* __restrict__ dst, int K, int N)
{
  __shared__ float t[64][65];
  int n0 = blockIdx.x*64, k0 = blockIdx.y*64;
  src += (size_t)blockIdx.z*K*N;
  dst += (size_t)blockIdx.z*N*K;
  int tid = threadIdx.x;
  int r = tid>>4, c4 = (tid&15)*4;
#pragma unroll
  for (int p=0;p<4;p++){
    int row = r + p*16;
    float4 v = *(const float4*)(src + (size_t)(k0+row)*N + n0 + c4);
    t[c4+0][row]=v.x; t[c4+1][row]=v.y; t[c4+2][row]=v.z; t[c4+3][row]=v.w;
  }
  __syncthreads();
  int rn = tid>>2, ch = tid&3;
  unsigned short o[16];
#pragma unroll
  for (int i=0;i<16;i++) o[i] = f2bf(t[rn][ch*16+i]);
  uint4* d = (uint4*)(dst + (size_t)(n0+rn)*K + k0 + ch*16);
  d[0] = ((uint4*)o)[0]; d[1] = ((uint4*)o)[1];
}

// ---------------------------------------------------------------------------
// LayerNorm fp32 -> bf16. One wave per row.
// ---------------------------------------------------------------------------
__global__ __launch_bounds__(256) void ln_kernel(const float* __restrict__ x,
    const float* __restrict__ g, const float* __restrict__ b,
    unsigned short* __restrict__ h)
{
  int row  = blockIdx.x*4 + (threadIdx.x>>6);
  int lane = threadIdx.x & 63;
  const float* xr = x + (size_t)row*DIM;
  float4 v[4]; float s=0.f, ss=0.f;
#pragma unroll
  for (int c=0;c<4;c++){
    v[c] = *(const float4*)(xr + c*256 + lane*4);
    s  += v[c].x+v[c].y+v[c].z+v[c].w;
    ss += v[c].x*v[c].x+v[c].y*v[c].y+v[c].z*v[c].z+v[c].w*v[c].w;
  }
#pragma unroll
  for (int o=1;o<64;o<<=1){ s += __shfl_xor(s,o); ss += __shfl_xor(ss,o); }
  float mu  = s*(1.f/1024.f);
  float var = ss*(1.f/1024.f) - mu*mu;
  float rstd = rsqrtf(var + 1e-5f);
#pragma unroll
  for (int c=0;c<4;c++){
    float4 gg = *(const float4*)(g + c*256 + lane*4);
    float4 bb = *(const float4*)(b + c*256 + lane*4);
    ushort4 o;
    o.x = f2bf((v[c].x-mu)*rstd*gg.x + bb.x);
    o.y = f2bf((v[c].y-mu)*rstd*gg.y + bb.y);
    o.z = f2bf((v[c].z-mu)*rstd*gg.z + bb.z);
    o.w = f2bf((v[c].w-mu)*rstd*gg.w + bb.w);
    *(ushort4*)(h + (size_t)row*DIM + c*256 + lane*4) = o;
  }
}

// ---------------------------------------------------------------------------
// V transpose: qkv bf16 [B*N][3072] (v cols 2048..3071) -> vT [B*H*64][N]
// ---------------------------------------------------------------------------
__global__ __launch_bounds__(256) void vtrans_kernel(
    const unsigned short* __restrict__ qkv, unsigned short* __restrict__ vT)
{
  __shared__ float t[64][65];
  int n0 = blockIdx.x*64;
  int bh = blockIdx.y; int b = bh>>4, hh = bh&15;
  int tid = threadIdx.x;
  int r = tid>>4, c4 = (tid&15)*4;
#pragma unroll
  for (int p=0;p<4;p++){
    int row = r + p*16;
    ushort4 u = *(const ushort4*)(qkv + (size_t)(b*NTOK + n0 + row)*3072 + 2048 + hh*64 + c4);
    t[c4+0][row]=bf2f(u.x); t[c4+1][row]=bf2f(u.y); t[c4+2][row]=bf2f(u.z); t[c4+3][row]=bf2f(u.w);
  }
  __syncthreads();
  int rn = tid>>2, ch = tid&3;
  unsigned short o[16];
#pragma unroll
  for (int i=0;i<16;i++) o[i] = f2bf(t[rn][ch*16+i]);
  uint4* d = (uint4*)(vT + (size_t)(bh*64 + rn)*NTOK + n0 + ch*16);
  d[0] = ((uint4*)o)[0]; d[1] = ((uint4*)o)[1];
}

// ---------------------------------------------------------------------------
// 128xBN m97-structure GEMM (kept for N=1024 outputs: Wout, MLP2).
// EPI 1: fp32 store of acc+res+bias.
// ---------------------------------------------------------------------------
template<int BN, int EPI>
__global__ __launch_bounds__(256) void gemm_kernel(
    const unsigned short* __restrict__ A,
    const unsigned short* __restrict__ Bt,
    unsigned short* __restrict__ outb,
    float* __restrict__ outf,
    const float* __restrict__ res,
    const float* __restrict__ bias,
    int M, int N, int K, int ldout)
{
  constexpr int BM=128, BK=64;
  constexpr int NT = BN/32;
  __shared__ unsigned short As[BM*BK];
  __shared__ unsigned short Bs[BN*BK];
  int tid = threadIdx.x, lane = tid&63, w = tid>>6;
  int wm = w&1, wn = w>>1;

  int gn  = N/BN;
  int nwg = (M/BM)*gn;
  int bid = blockIdx.x;
  int id  = (nwg%8==0) ? ((bid&7)*(nwg>>3) + (bid>>3)) : bid;
  int m0 = (id/gn)*BM, n0 = (id%gn)*BN;

  f32x4 acc[4][NT] = {};

  for (int k0=0; k0<K; k0+=BK){
    __syncthreads();
#pragma unroll
    for (int i=0;i<4;i++){
      int off = w*4096 + i*1024 + lane*16;
      int row = off>>7, p = (off&127)>>4;
      async16(A + (size_t)(m0+row)*K + k0 + ((p^(row&7))<<3),
              (char*)As + w*4096 + i*1024);
    }
#pragma unroll
    for (int i=0;i<NT;i++){
      int off = w*(BN*32) + i*1024 + lane*16;
      int row = off>>7, p = (off&127)>>4;
      async16(Bt + (size_t)(n0+row)*K + k0 + ((p^(row&7))<<3),
              (char*)Bs + w*(BN*32) + i*1024);
    }
    __syncthreads();
#pragma unroll
    for (int ks=0;ks<2;ks++){
      s16x8 a[4], bfr[NT];
#pragma unroll
      for (int mt=0;mt<4;mt++){
        int row = wm*64 + mt*16 + (lane&15);
        int c = (ks*4 + (lane>>4)) ^ (row&7);
        a[mt] = *(const s16x8*)((const char*)As + row*128 + c*16);
      }
#pragma unroll
      for (int nt=0;nt<NT;nt++){
        int row = wn*(BN/2) + nt*16 + (lane&15);
        int c = (ks*4 + (lane>>4)) ^ (row&7);
        bfr[nt] = *(const s16x8*)((const char*)Bs + row*128 + c*16);
      }
#pragma unroll
      for (int mt=0;mt<4;mt++)
#pragma unroll
        for (int nt=0;nt<NT;nt++)
          acc[mt][nt] = MFMA(a[mt], bfr[nt], acc[mt][nt]);
    }
  }

#pragma unroll
  for (int mt=0;mt<4;mt++)
#pragma unroll
    for (int nt=0;nt<NT;nt++)
#pragma unroll
      for (int r=0;r<4;r++){
        int row = m0 + wm*64 + mt*16 + ((lane>>4)<<2) + r;
        int col = n0 + wn*(BN/2) + nt*16 + (lane&15);
        float v = acc[mt][nt][r];
        if (EPI==0){
          outb[(size_t)row*ldout + col] = f2bf(v);
        } else if (EPI==1){
          float t = v + res[(size_t)row*ldout + col] + bias[col];
          outf[(size_t)row*ldout + col] = t;
        } else {
          float t = v + bias[col];
          t = 0.5f*t*(1.f + erff(t*0.70710678118f));
          outb[(size_t)row*ldout + col] = f2bf(t);
        }
      }
}

// ---------------------------------------------------------------------------
// 256x256 8-phase deep-pipelined GEMM (T2+T3+T4+T5).
// 512 thr = 8 waves (2M x 4N), wave tile 128x64, BK=64, LDS 128 KiB dbuf.
// Counted vmcnt(4) once per K-tile; staging halves: P0:(t+1)B0 P1:(t+1)B1
// P2:(t+2)A0 P3:(t+2)A1 (A overwrite legal: all A-reads finish by P1).
// EPI 0: bf16 store (QKV). EPI 2: bias+gelu bf16 (MLP1).
// ---------------------------------------------------------------------------
template<int EPI>
__global__ __launch_bounds__(512,2) void gemm256_kernel(
    const unsigned short* __restrict__ A,
    const unsigned short* __restrict__ Bt,
    unsigned short* __restrict__ outb,
    const float* __restrict__ bias,
    int M, int N, int K, int ldout)
{
  __shared__ unsigned short lds[2][2][256*64];   // [buf][A|B][row*64+col], chunk-swizzled
  const int tid = threadIdx.x, lane = tid&63, w = tid>>6;
  const int wm = w>>2, wn = w&3;
  const int gn = N>>8;
  const int nwg = (M>>8)*gn;
  const int q = nwg>>3, r = nwg&7;
  const int xc = blockIdx.x&7, od = blockIdx.x>>3;
  const int id = (xc<r ? xc*(q+1) : r*(q+1)+(xc-r)*q) + od;   // m204 bijective
  const int m0 = (id/gn)<<8, n0 = (id%gn)<<8;
  const int nkt = K>>6;

  f32x4 acc[8][4] = {};
  s16x8 af[8][2];
  s16x8 bf[2][2];

  auto stage = [&](int bsel, int half, int kt){
    const unsigned short* src = (half<2) ? A : Bt;
    const int base0 = (half<2) ? m0 : n0;
    const int rbase = (half&1)<<7;
    char* dstbase = (char*)lds[bsel][half>>1] + (rbase<<7);
#pragma unroll
    for (int i=0;i<2;i++){
      int off  = ((w<<1)+i)<<10;
      int loff = off + lane*16;
      int row  = loff>>7, p = (loff&127)>>4;
      async16(src + (size_t)(base0+rbase+row)*K + (kt<<6) + ((p^(row&7))<<3),
              dstbase + off);
    }
  };

#define LDA(mt,ks) { int rw=(wm<<7)+((mt)<<4)+(lane&15); int pc=(((ks)<<2)+(lane>>4))^(rw&7); \
  af[mt][ks] = *(const s16x8*)((const char*)lds[cur][0] + rw*128 + (pc<<4)); }
#define LDB(j,nt,ks) { int rw=(wn<<6)+((nt)<<4)+(lane&15); int pc=(((ks)<<2)+(lane>>4))^(rw&7); \
  bf[j][ks] = *(const s16x8*)((const char*)lds[cur][1] + rw*128 + (pc<<4)); }

  // prologue: tile0 all 4 halves + tile1 A0,A1 -> 12 loads; retire tile0.
  stage(0,0,0); stage(0,1,0); stage(0,2,0); stage(0,3,0);
  stage(1,0,1); stage(1,1,1);
  asm volatile("s_waitcnt vmcnt(4)" ::: "memory");
  __builtin_amdgcn_s_barrier();

  for (int t=0; t<nkt; ++t){
    const int cur = t&1, nxt = cur^1;
    // ---- P0: read A[mh0] + B[nh0]; stage (t+1)B0; MFMA q(mh0,nh0)
#pragma unroll
    for (int mt=0;mt<4;mt++){ LDA(mt,0); LDA(mt,1); }
#pragma unroll
    for (int nt=0;nt<2;nt++){ LDB(nt,nt,0); LDB(nt,nt,1); }
    if (t+1<nkt) stage(nxt,2,t+1);
    __builtin_amdgcn_s_barrier();
    asm volatile("s_waitcnt lgkmcnt(0)" ::: "memory");
    __builtin_amdgcn_sched_barrier(0);
    __builtin_amdgcn_s_setprio(1);
#pragma unroll
    for (int mt=0;mt<4;mt++)
#pragma unroll
      for (int nt=0;nt<2;nt++){
        acc[mt][nt] = MFMA(af[mt][0], bf[nt][0], acc[mt][nt]);
        acc[mt][nt] = MFMA(af[mt][1], bf[nt][1], acc[mt][nt]);
      }
    __builtin_amdgcn_s_setprio(0);
    __builtin_amdgcn_s_barrier();
    // ---- P1: read A[mh1]; stage (t+1)B1; MFMA q(mh1,nh0)
#pragma unroll
    for (int mt=4;mt<8;mt++){ LDA(mt,0); LDA(mt,1); }
    if (t+1<nkt) stage(nxt,3,t+1);
    __builtin_amdgcn_s_barrier();
    asm volatile("s_waitcnt lgkmcnt(0)" ::: "memory");
    __builtin_amdgcn_sched_barrier(0);
    __builtin_amdgcn_s_setprio(1);
#pragma unroll
    for (int mt=4;mt<8;mt++)
#pragma unroll
      for (int nt=0;nt<2;nt++){
        acc[mt][nt] = MFMA(af[mt][0], bf[nt][0], acc[mt][nt]);
        acc[mt][nt] = MFMA(af[mt][1], bf[nt][1], acc[mt][nt]);
      }
    __builtin_amdgcn_s_setprio(0);
    __builtin_amdgcn_s_barrier();
    // ---- P2: read B[nh1] (reuse regs); stage (t+2)A0; MFMA q(mh0,nh1)
#pragma unroll
    for (int nt=0;nt<2;nt++){ LDB(nt,nt+2,0); LDB(nt,nt+2,1); }
    if (t+2<nkt) stage(cur,0,t+2);
    __builtin_amdgcn_s_barrier();
    asm volatile("s_waitcnt lgkmcnt(0)" ::: "memory");
    __builtin_amdgcn_sched_barrier(0);
    __builtin_amdgcn_s_setprio(1);
#pragma unroll
    for (int mt=0;mt<4;mt++)
#pragma unroll
      for (int nt=0;nt<2;nt++){
        acc[mt][nt+2] = MFMA(af[mt][0], bf[nt][0], acc[mt][nt+2]);
        acc[mt][nt+2] = MFMA(af[mt][1], bf[nt][1], acc[mt][nt+2]);
      }
    __builtin_amdgcn_s_setprio(0);
    __builtin_amdgcn_s_barrier();
    // ---- P3: stage (t+2)A1; MFMA q(mh1,nh1); counted vmcnt retiring t+1
    if (t+2<nkt) stage(cur,1,t+2);
    __builtin_amdgcn_s_barrier();
    __builtin_amdgcn_s_setprio(1);
#pragma unroll
    for (int mt=4;mt<8;mt++)
#pragma unroll
      for (int nt=0;nt<2;nt++){
        acc[mt][nt+2] = MFMA(af[mt][0], bf[nt][0], acc[mt][nt+2]);
        acc[mt][nt+2] = MFMA(af[mt][1], bf[nt][1], acc[mt][nt+2]);
      }
    __builtin_amdgcn_s_setprio(0);
    if (t+2<nkt) asm volatile("s_waitcnt vmcnt(4)" ::: "memory");
    else         asm volatile("s_waitcnt vmcnt(0)" ::: "memory");
    __builtin_amdgcn_s_barrier();
  }
#undef LDA
#undef LDB

#pragma unroll
  for (int mt=0;mt<8;mt++)
#pragma unroll
    for (int nt=0;nt<4;nt++)
#pragma unroll
      for (int rr=0;rr<4;rr++){
        int row = m0 + (wm<<7) + (mt<<4) + ((lane>>4)<<2) + rr;
        int col = n0 + (wn<<6) + (nt<<4) + (lane&15);
        float v = acc[mt][nt][rr];
        if (EPI==2){
          v += bias[col];
          v = 0.5f*v*(1.f + erff(v*0.70710678118f));
        }
        outb[(size_t)row*ldout + col] = f2bf(v);
      }
}

// ---------------------------------------------------------------------------
// Flash attention, double-buffered K/V staging with counted vmcnt (T3/T4 min
// form) + setprio (T5) + deferred per-lane partial row-sums.
// ---------------------------------------------------------------------------
__global__ __launch_bounds__(256) void attn_kernel(
    const unsigned short* __restrict__ qkv,   // [B*N][3072]
    const unsigned short* __restrict__ vT,    // [B*H*64][N]
    const int* __restrict__ mnp, const int* __restrict__ mbert,
    unsigned short* __restrict__ outb)        // [B*N][1024]
{
  __shared__ unsigned short Ks[2][64*64];
  __shared__ unsigned short Vs[2][64*64];
  __shared__ unsigned short Pb[4][16*64];
  __shared__ float fm[NTOK];
  int qt = blockIdx.x, bh = blockIdx.y;
  int b = bh>>4, hh = bh&15;
  int tid = threadIdx.x, lane = tid&63, w = tid>>6;

  for (int j = tid; j < NTOK; j += 256)
    fm[j] = (mnp[b*NTOK+j]==0 || mbert[b*NTOK+j]==1) ? 1.f : 0.f;

  int iA = qt*64 + w*16 + (lane&15);
  s16x8 aq[2];
#pragma unroll
  for (int ks=0;ks<2;ks++)
    aq[ks] = *(const s16x8*)(qkv + (size_t)(b*NTOK+iA)*3072 + hh*64 + ks*32 + ((lane>>4)<<3));

  bool rowm[4]; float mreg[4], lsum[4]; f32x4 o[4];
#pragma unroll
  for (int r=0;r<4;r++){
    int i = qt*64 + w*16 + ((lane>>4)<<2) + r;
    rowm[r] = (mnp[b*NTOK+i]==0);
    mreg[r] = -1e30f; lsum[r] = 0.f;
    o[r] = f32x4{0.f,0.f,0.f,0.f};
  }
  __syncthreads();   // fm visible to all waves

  auto stageKV = [&](int bufi, int kc){
    int j0 = kc<<6;
#pragma unroll
    for (int i=0;i<2;i++){
      int off  = w*2048 + i*1024;
      int loff = off + lane*16;
      int row  = loff>>7, p = (loff&127)>>4;
      async16(qkv + (size_t)(b*NTOK + j0 + row)*3072 + 1024 + hh*64 + ((p^(row&7))<<3),
              (char*)Ks[bufi] + off);
      async16(vT + (size_t)(bh*64 + row)*NTOK + j0 + ((p^(row&7))<<3),
              (char*)Vs[bufi] + off);
    }
  };

  stageKV(0,0);

  for (int kc=0; kc<16; kc++){
    int cur = kc&1;
    int j0 = kc*64;
    if (kc<15) stageKV(cur^1, kc+1);
    if (kc<15) asm volatile("s_waitcnt vmcnt(4)" ::: "memory");
    else       asm volatile("s_waitcnt vmcnt(0)" ::: "memory");
    __builtin_amdgcn_s_barrier();

    f32x4 sc[4];
    __builtin_amdgcn_s_setprio(1);
#pragma unroll
    for (int jt=0;jt<4;jt++){
      sc[jt] = f32x4{0.f,0.f,0.f,0.f};
#pragma unroll
      for (int ks=0;ks<2;ks++){
        int row = jt*16 + (lane&15);
        int c = (ks*4 + (lane>>4)) ^ (row&7);
        s16x8 bk = *(const s16x8*)((const char*)Ks[cur] + row*128 + c*16);
        sc[jt] = MFMA(aq[ks], bk, sc[jt]);
      }
    }
    __builtin_amdgcn_s_setprio(0);
#pragma unroll
    for (int jt=0;jt<4;jt++){
      float f = fm[j0 + jt*16 + (lane&15)];
#pragma unroll
      for (int r=0;r<4;r++){
        float s = sc[jt][r]*SCALE;
        sc[jt][r] = (f!=0.f || rowm[r]) ? -1000.f : s;
      }
    }
#pragma unroll
    for (int r=0;r<4;r++){
      float mx = fmaxf(fmaxf(sc[0][r],sc[1][r]), fmaxf(sc[2][r],sc[3][r]));
#pragma unroll
      for (int ofs=8;ofs>=1;ofs>>=1) mx = fmaxf(mx, __shfl_xor(mx, ofs));
      float mnew  = fmaxf(mreg[r], mx);
      float alpha = __expf(mreg[r]-mnew);
      mreg[r] = mnew;
      float rs = 0.f;
#pragma unroll
      for (int jt=0;jt<4;jt++){ float p = __expf(sc[jt][r]-mnew); sc[jt][r]=p; rs+=p; }
      lsum[r] = lsum[r]*alpha + rs;       // per-lane partial; reduced at end
#pragma unroll
      for (int nt=0;nt<4;nt++) o[nt][r] *= alpha;
    }
#pragma unroll
    for (int jt=0;jt<4;jt++)
#pragma unroll
      for (int r=0;r<4;r++){
        int ir = ((lane>>4)<<2)+r, jc = jt*16+(lane&15);
        int byteoff = ir*128 + ((((jc>>3))^(ir&7))<<4) + ((jc&7)<<1);
        *((unsigned short*)((char*)Pb[w] + byteoff)) = f2bf(sc[jt][r]);
      }
    __builtin_amdgcn_s_setprio(1);
#pragma unroll
    for (int ks=0;ks<2;ks++){
      int rowp = lane&15;
      int cp = (ks*4 + (lane>>4)) ^ (rowp&7);
      s16x8 ap = *(const s16x8*)((const char*)Pb[w] + rowp*128 + cp*16);
#pragma unroll
      for (int nt=0;nt<4;nt++){
        int d = nt*16 + (lane&15);
        int c = (ks*4 + (lane>>4)) ^ (d&7);
        s16x8 bv = *(const s16x8*)((const char*)Vs[cur] + d*128 + c*16);
        o[nt] = MFMA(ap, bv, o[nt]);
      }
    }
    __builtin_amdgcn_s_setprio(0);
    __builtin_amdgcn_s_barrier();
  }

#pragma unroll
  for (int r=0;r<4;r++){
#pragma unroll
    for (int ofs=8;ofs>=1;ofs>>=1) lsum[r] += __shfl_xor(lsum[r], ofs);
    float inv = 1.f/lsum[r];
    int i = qt*64 + w*16 + ((lane>>4)<<2) + r;
#pragma unroll
    for (int nt=0;nt<4;nt++){
      int d = nt*16 + (lane&15);
      outb[(size_t)(b*NTOK+i)*DIM + hh*64 + d] = f2bf(o[nt][r]*inv);
    }
  }
}

// ---------------------------------------------------------------------------
extern "C" void kernel_launch(void* const* d_in, const int* in_sizes, int n_in,
                              void* d_out, int out_size, void* d_ws, size_t ws_size,
                              hipStream_t stream)
{
  const float* xin0 = (const float*)d_in[0];
  const float* Wqkv = (const float*)d_in[1];
  const float* Wout = (const float*)d_in[2];
  const float* bout = (const float*)d_in[3];
  const float* ln1g = (const float*)d_in[4];
  const float* ln1b = (const float*)d_in[5];
  const float* W1   = (const float*)d_in[6];
  const float* b1   = (const float*)d_in[7];
  const float* W2   = (const float*)d_in[8];
  const float* b2   = (const float*)d_in[9];
  const float* ln2g = (const float*)d_in[10];
  const float* ln2b = (const float*)d_in[11];
  const int*   mnp  = (const int*)d_in[12];
  const int*   mbt  = (const int*)d_in[13];
  float* out = (float*)d_out;

  unsigned short* Wqkv_t = (unsigned short*)d_ws;
  unsigned short* Wout_t = Wqkv_t + (size_t)4*3072*1024;
  unsigned short* W1_t   = Wout_t + (size_t)4*1024*1024;
  unsigned short* W2_t   = W1_t   + (size_t)4*4096*1024;
  float*          x      = (float*)(W2_t + (size_t)4*1024*4096);
  unsigned short* hbuf   = (unsigned short*)(x + (size_t)ROWS*DIM);
  unsigned short* qkvb   = hbuf  + (size_t)ROWS*DIM;
  unsigned short* vTb    = qkvb  + (size_t)ROWS*3072;
  unsigned short* attnb  = vTb   + (size_t)ROWS*DIM;
  unsigned short* gbuf   = attnb + (size_t)ROWS*DIM;

  wt_kernel<<<dim3(3072/64,1024/64,4),256,0,stream>>>(Wqkv, Wqkv_t, 1024, 3072);
  wt_kernel<<<dim3(1024/64,1024/64,4),256,0,stream>>>(Wout, Wout_t, 1024, 1024);
  wt_kernel<<<dim3(4096/64,1024/64,4),256,0,stream>>>(W1,   W1_t,   1024, 4096);
  wt_kernel<<<dim3(1024/64,4096/64,4),256,0,stream>>>(W2,   W2_t,   4096, 1024);

  for (int l=0;l<4;l++){
    const float* xres = (l==0) ? xin0 : x;
    ln_kernel<<<1024,256,0,stream>>>(xres, ln1g+l*DIM, ln1b+l*DIM, hbuf);
    gemm256_kernel<0><<<192,512,0,stream>>>(hbuf, Wqkv_t + (size_t)l*3072*1024,
        qkvb, nullptr, ROWS, 3072, 1024, 3072);
    vtrans_kernel<<<dim3(16,64),256,0,stream>>>(qkvb, vTb);
    attn_kernel<<<dim3(16,64),256,0,stream>>>(qkvb, vTb, mnp, mbt, attnb);
    gemm_kernel<64,1><<<512,256,0,stream>>>(attnb, Wout_t + (size_t)l*1024*1024,
        nullptr, x, xres, bout+l*DIM, ROWS, 1024, 1024, 1024);
    ln_kernel<<<1024,256,0,stream>>>(x, ln2g+l*DIM, ln2b+l*DIM, hbuf);
    gemm256_kernel<2><<<256,512,0,stream>>>(hbuf, W1_t + (size_t)l*4096*1024,
        gbuf, b1+l*MLPD, ROWS, 4096, 1024, 4096);
    float* xo = (l==3) ? out : x;
    gemm_kernel<64,1><<<512,256,0,stream>>>(gbuf, W2_t + (size_t)l*1024*4096,
        nullptr, xo, x, b2+l*DIM, ROWS, 1024, 4096, 1024);
  }
}

// Round 3
// 1193.408 us; speedup vs baseline: 1.0544x; 1.0197x over previous
//
#include <hip/hip_runtime.h>
#include <hip/hip_bf16.h>

#define DEPTH 4
#define HEADS 16
#define DIMH  64
#define DIM   1024
#define MLPD  4096
#define NTOK  1024
#define BATCH 4
#define ROWS  (BATCH*NTOK)      // 4096
#define SCALE 0.125f            // 64^-0.5

typedef float f32x4 __attribute__((ext_vector_type(4)));
typedef short s16x8 __attribute__((ext_vector_type(8)));

#define MFMA(a,b,c) __builtin_amdgcn_mfma_f32_16x16x32_bf16((a),(b),(c),0,0,0)

__device__ __forceinline__ unsigned short f2bf(float f){
  union{ __hip_bfloat16 h; unsigned short u; } x; x.h = __float2bfloat16(f); return x.u;
}
__device__ __forceinline__ float bf2f(unsigned short u){
  return __uint_as_float(((unsigned)u)<<16);
}

__device__ __forceinline__ void async16(const void* g, void* l){
  __builtin_amdgcn_global_load_lds(
      (const __attribute__((address_space(1))) void*)g,
      (__attribute__((address_space(3))) void*)l, 16, 0, 0);
}

// ---------------------------------------------------------------------------
// Weight convert+transpose: src fp32 [D][K][N] -> dst bf16(ushort) [D][N][K]
// ---------------------------------------------------------------------------
__global__ __launch_bounds__(256) void wt_kernel(const float* __restrict__ src,
    unsigned short* __restrict__ dst, int K, int N)
{
  __shared__ float t[64][65];
  int n0 = blockIdx.x*64, k0 = blockIdx.y*64;
  src += (size_t)blockIdx.z*K*N;
  dst += (size_t)blockIdx.z*N*K;
  int tid = threadIdx.x;
  int r = tid>>4, c4 = (tid&15)*4;
#pragma unroll
  for (int p=0;p<4;p++){
    int row = r + p*16;
    float4 v = *(const float4*)(src + (size_t)(k0+row)*N + n0 + c4);
    t[c4+0][row]=v.x; t[c4+1][row]=v.y; t[c4+2][row]=v.z; t[c4+3][row]=v.w;
  }
  __syncthreads();
  int rn = tid>>2, ch = tid&3;
  unsigned short o[16];
#pragma unroll
  for (int i=0;i<16;i++) o[i] = f2bf(t[rn][ch*16+i]);
  uint4* d = (uint4*)(dst + (size_t)(n0+rn)*K + k0 + ch*16);
  d[0] = ((uint4*)o)[0]; d[1] = ((uint4*)o)[1];
}

// ---------------------------------------------------------------------------
// LayerNorm fp32 -> bf16. One wave per row.
// ---------------------------------------------------------------------------
__global__ __launch_bounds__(256) void ln_kernel(const float* __restrict__ x,
    const float* __restrict__ g, const float* __restrict__ b,
    unsigned short* __restrict__ h)
{
  int row  = blockIdx.x*4 + (threadIdx.x>>6);
  int lane = threadIdx.x & 63;
  const float* xr = x + (size_t)row*DIM;
  float4 v[4]; float s=0.f, ss=0.f;
#pragma unroll
  for (int c=0;c<4;c++){
    v[c] = *(const float4*)(xr + c*256 + lane*4);
    s  += v[c].x+v[c].y+v[c].z+v[c].w;
    ss += v[c].x*v[c].x+v[c].y*v[c].y+v[c].z*v[c].z+v[c].w*v[c].w;
  }
#pragma unroll
  for (int o=1;o<64;o<<=1){ s += __shfl_xor(s,o); ss += __shfl_xor(ss,o); }
  float mu  = s*(1.f/1024.f);
  float var = ss*(1.f/1024.f) - mu*mu;
  float rstd = rsqrtf(var + 1e-5f);
#pragma unroll
  for (int c=0;c<4;c++){
    float4 gg = *(const float4*)(g + c*256 + lane*4);
    float4 bb = *(const float4*)(b + c*256 + lane*4);
    ushort4 o;
    o.x = f2bf((v[c].x-mu)*rstd*gg.x + bb.x);
    o.y = f2bf((v[c].y-mu)*rstd*gg.y + bb.y);
    o.z = f2bf((v[c].z-mu)*rstd*gg.z + bb.z);
    o.w = f2bf((v[c].w-mu)*rstd*gg.w + bb.w);
    *(ushort4*)(h + (size_t)row*DIM + c*256 + lane*4) = o;
  }
}

// ---------------------------------------------------------------------------
// V transpose: qkv bf16 [B*N][3072] (v cols 2048..3071) -> vT [B*H*64][N]
// ---------------------------------------------------------------------------
__global__ __launch_bounds__(256) void vtrans_kernel(
    const unsigned short* __restrict__ qkv, unsigned short* __restrict__ vT)
{
  __shared__ float t[64][65];
  int n0 = blockIdx.x*64;
  int bh = blockIdx.y; int b = bh>>4, hh = bh&15;
  int tid = threadIdx.x;
  int r = tid>>4, c4 = (tid&15)*4;
#pragma unroll
  for (int p=0;p<4;p++){
    int row = r + p*16;
    ushort4 u = *(const ushort4*)(qkv + (size_t)(b*NTOK + n0 + row)*3072 + 2048 + hh*64 + c4);
    t[c4+0][row]=bf2f(u.x); t[c4+1][row]=bf2f(u.y); t[c4+2][row]=bf2f(u.z); t[c4+3][row]=bf2f(u.w);
  }
  __syncthreads();
  int rn = tid>>2, ch = tid&3;
  unsigned short o[16];
#pragma unroll
  for (int i=0;i<16;i++) o[i] = f2bf(t[rn][ch*16+i]);
  uint4* d = (uint4*)(vT + (size_t)(bh*64 + rn)*NTOK + n0 + ch*16);
  d[0] = ((uint4*)o)[0]; d[1] = ((uint4*)o)[1];
}

// ---------------------------------------------------------------------------
// 128x64 m97-structure GEMM, kept for Wout (N=1024, fused res+bias fp32 out).
// ---------------------------------------------------------------------------
template<int BN, int EPI>
__global__ __launch_bounds__(256) void gemm_kernel(
    const unsigned short* __restrict__ A,
    const unsigned short* __restrict__ Bt,
    unsigned short* __restrict__ outb,
    float* __restrict__ outf,
    const float* __restrict__ res,
    const float* __restrict__ bias,
    int M, int N, int K, int ldout)
{
  constexpr int BM=128, BK=64;
  constexpr int NT = BN/32;
  __shared__ unsigned short As[BM*BK];
  __shared__ unsigned short Bs[BN*BK];
  int tid = threadIdx.x, lane = tid&63, w = tid>>6;
  int wm = w&1, wn = w>>1;

  int gn  = N/BN;
  int nwg = (M/BM)*gn;
  int bid = blockIdx.x;
  int id  = (nwg%8==0) ? ((bid&7)*(nwg>>3) + (bid>>3)) : bid;
  int m0 = (id/gn)*BM, n0 = (id%gn)*BN;

  f32x4 acc[4][NT] = {};

  for (int k0=0; k0<K; k0+=BK){
    __syncthreads();
#pragma unroll
    for (int i=0;i<4;i++){
      int off = w*4096 + i*1024 + lane*16;
      int row = off>>7, p = (off&127)>>4;
      async16(A + (size_t)(m0+row)*K + k0 + ((p^(row&7))<<3),
              (char*)As + w*4096 + i*1024);
    }
#pragma unroll
    for (int i=0;i<NT;i++){
      int off = w*(BN*32) + i*1024 + lane*16;
      int row = off>>7, p = (off&127)>>4;
      async16(Bt + (size_t)(n0+row)*K + k0 + ((p^(row&7))<<3),
              (char*)Bs + w*(BN*32) + i*1024);
    }
    __syncthreads();
#pragma unroll
    for (int ks=0;ks<2;ks++){
      s16x8 a[4], bfr[NT];
#pragma unroll
      for (int mt=0;mt<4;mt++){
        int row = wm*64 + mt*16 + (lane&15);
        int c = (ks*4 + (lane>>4)) ^ (row&7);
        a[mt] = *(const s16x8*)((const char*)As + row*128 + c*16);
      }
#pragma unroll
      for (int nt=0;nt<NT;nt++){
        int row = wn*(BN/2) + nt*16 + (lane&15);
        int c = (ks*4 + (lane>>4)) ^ (row&7);
        bfr[nt] = *(const s16x8*)((const char*)Bs + row*128 + c*16);
      }
#pragma unroll
      for (int mt=0;mt<4;mt++)
#pragma unroll
        for (int nt=0;nt<NT;nt++)
          acc[mt][nt] = MFMA(a[mt], bfr[nt], acc[mt][nt]);
    }
  }

#pragma unroll
  for (int mt=0;mt<4;mt++)
#pragma unroll
    for (int nt=0;nt<NT;nt++)
#pragma unroll
      for (int r=0;r<4;r++){
        int row = m0 + wm*64 + mt*16 + ((lane>>4)<<2) + r;
        int col = n0 + wn*(BN/2) + nt*16 + (lane&15);
        float v = acc[mt][nt][r];
        if (EPI==0){
          outb[(size_t)row*ldout + col] = f2bf(v);
        } else if (EPI==1){
          float t = v + res[(size_t)row*ldout + col] + bias[col];
          outf[(size_t)row*ldout + col] = t;
        } else {
          float t = v + bias[col];
          t = 0.5f*t*(1.f + erff(t*0.70710678118f));
          outb[(size_t)row*ldout + col] = f2bf(t);
        }
      }
}

// ---------------------------------------------------------------------------
// 256x256 BK=32 triple-buffered GEMM. 512 thr = 8 waves (2M x 4N), wave tile
// 128x64. LDS 96KB = 3 bufs x (A 16KB + B 16KB), 64B rows -> bank-uniform
// ds_read_b128 without swizzle. Schedule per K-step t: stage T(t+2) into
// buf (t+2)%3 (WAR sealed by iter t-1's end barrier), ds_read buf t%3, 32
// MFMA, vmcnt(4) retires T(t+1) (staged one full step ago), barrier.
// Optional split-K: SK partial outputs (EPI0 bf16) combined by mlp2add.
// EPI 0: bf16 store. EPI 2: bias+gelu bf16.
// ---------------------------------------------------------------------------
template<int EPI>
__global__ __launch_bounds__(512,2) void gemm_tb_kernel(
    const unsigned short* __restrict__ A,   // [M][lda]
    const unsigned short* __restrict__ Bt,  // [N][lda]
    unsigned short* __restrict__ outb,
    const float* __restrict__ bias,
    int M, int N, int K, int lda, int ldout, int SK, size_t oslab)
{
  __shared__ unsigned short lds[3][2][256*32];
  const int tid = threadIdx.x, lane = tid&63, w = tid>>6;
  const int wm = w>>2, wn = w&3;
  const int gn = N>>8;
  const int ntile = (M>>8)*gn;
  const int nwg = ntile*SK;
  int id;
  { const int q = nwg>>3, r = nwg&7, xc = blockIdx.x&7, od = blockIdx.x>>3;
    id = (xc<r ? xc*(q+1) : r*(q+1)+(xc-r)*q) + od; }
  const int sk = id/ntile, tt = id%ntile;
  const int m0 = (tt/gn)<<8, n0 = (tt%gn)<<8;
  const int kbase = sk*K;
  unsigned short* outp = outb + (size_t)sk*oslab;
  const int nkt = K>>5;

  f32x4 acc[8][4] = {};

  auto stage = [&](int bsel, int kt){
    const int k0 = kbase + (kt<<5);
#pragma unroll
    for (int i=0;i<2;i++){
      int off  = ((w<<1)+i)<<10;
      int loff = off + lane*16;
      int row  = loff>>6, cl = (loff&63)>>4;
      async16(A + (size_t)(m0+row)*lda + k0 + (cl<<3),
              (char*)lds[bsel][0] + off);
    }
#pragma unroll
    for (int i=0;i<2;i++){
      int off  = ((w<<1)+i)<<10;
      int loff = off + lane*16;
      int row  = loff>>6, cl = (loff&63)>>4;
      async16(Bt + (size_t)(n0+row)*lda + k0 + (cl<<3),
              (char*)lds[bsel][1] + off);
    }
  };

  stage(0,0); stage(1,1);
  asm volatile("s_waitcnt vmcnt(4)" ::: "memory");
  __builtin_amdgcn_s_barrier();

  int cb = 0;
  for (int t=0; t<nkt; ++t){
    int sb = cb+2; if (sb>=3) sb -= 3;
    if (t+2<nkt) stage(sb, t+2);
    s16x8 af[8], bf[4];
#pragma unroll
    for (int mt=0;mt<8;mt++){
      int rw = (wm<<7) + (mt<<4) + (lane&15);
      af[mt] = *(const s16x8*)((const char*)lds[cb][0] + rw*64 + ((lane>>4)<<4));
    }
#pragma unroll
    for (int nt=0;nt<4;nt++){
      int rw = (wn<<6) + (nt<<4) + (lane&15);
      bf[nt] = *(const s16x8*)((const char*)lds[cb][1] + rw*64 + ((lane>>4)<<4));
    }
    __builtin_amdgcn_s_setprio(1);
#pragma unroll
    for (int mt=0;mt<8;mt++)
#pragma unroll
      for (int nt=0;nt<4;nt++)
        acc[mt][nt] = MFMA(af[mt], bf[nt], acc[mt][nt]);
    __builtin_amdgcn_s_setprio(0);
    if (t+2<nkt) asm volatile("s_waitcnt vmcnt(4)" ::: "memory");
    else         asm volatile("s_waitcnt vmcnt(0)" ::: "memory");
    __builtin_amdgcn_s_barrier();
    cb = cb+1; if (cb>=3) cb = 0;
  }

#pragma unroll
  for (int mt=0;mt<8;mt++)
#pragma unroll
    for (int nt=0;nt<4;nt++)
#pragma unroll
      for (int rr=0;rr<4;rr++){
        int row = m0 + (wm<<7) + (mt<<4) + ((lane>>4)<<2) + rr;
        int col = n0 + (wn<<6) + (nt<<4) + (lane&15);
        float v = acc[mt][nt][rr];
        if (EPI==2){
          v += bias[col];
          v = 0.5f*v*(1.f + erff(v*0.70710678118f));
        }
        outp[(size_t)row*ldout + col] = f2bf(v);
      }
}

// ---------------------------------------------------------------------------
// MLP2 split-K combine: out = x + b2 + sum of 4 bf16 partial planes.
// ---------------------------------------------------------------------------
__global__ __launch_bounds__(256) void mlp2add_kernel(
    const unsigned short* __restrict__ p, const float* __restrict__ x,
    const float* __restrict__ b2, float* __restrict__ out)
{
  int idx = blockIdx.x*256 + threadIdx.x;
  int i4 = idx<<2;
  int col = i4 & (DIM-1);
  float4 v = *(const float4*)(x + i4);
  float4 bb = *(const float4*)(b2 + col);
  v.x+=bb.x; v.y+=bb.y; v.z+=bb.z; v.w+=bb.w;
#pragma unroll
  for (int s=0;s<4;s++){
    ushort4 u = *(const ushort4*)(p + (size_t)s*ROWS*DIM + i4);
    v.x += bf2f(u.x); v.y += bf2f(u.y); v.z += bf2f(u.z); v.w += bf2f(u.w);
  }
  *(float4*)(out + i4) = v;
}

// ---------------------------------------------------------------------------
// Flash attention. QBLK=128 (4 waves x 2 strips x 16 q-rows), KVBLK=64,
// double-buffered K/V via global_load_lds + counted vmcnt, T13 defer-max,
// per-lane partial row-sums reduced once at the end.
// ---------------------------------------------------------------------------
__global__ __launch_bounds__(256) void attn_kernel(
    const unsigned short* __restrict__ qkv,   // [B*N][3072]
    const unsigned short* __restrict__ vT,    // [B*H*64][N]
    const int* __restrict__ mnp, const int* __restrict__ mbert,
    unsigned short* __restrict__ outb)        // [B*N][1024]
{
  __shared__ unsigned short Ks[2][64*64];
  __shared__ unsigned short Vs[2][64*64];
  __shared__ unsigned short Pb[4][2][16*64];
  __shared__ float fm[NTOK];
  int qt = blockIdx.x, bh = blockIdx.y;
  int b = bh>>4, hh = bh&15;
  int tid = threadIdx.x, lane = tid&63, w = tid>>6;

  for (int j = tid; j < NTOK; j += 256)
    fm[j] = (mnp[b*NTOK+j]==0 || mbert[b*NTOK+j]==1) ? 1.f : 0.f;

  s16x8 aq[2][2];
  bool rowm[2][4]; float mreg[2][4], lsum[2][4]; f32x4 o[2][4];
#pragma unroll
  for (int s=0;s<2;s++){
    int iA = qt*128 + s*64 + w*16 + (lane&15);
#pragma unroll
    for (int ks=0;ks<2;ks++)
      aq[s][ks] = *(const s16x8*)(qkv + (size_t)(b*NTOK+iA)*3072 + hh*64 + ks*32 + ((lane>>4)<<3));
#pragma unroll
    for (int nt=0;nt<4;nt++){
      int i = qt*128 + s*64 + w*16 + ((lane>>4)<<2) + nt;
      rowm[s][nt] = (mnp[b*NTOK+i]==0);
      mreg[s][nt] = -1e30f; lsum[s][nt] = 0.f;
      o[s][nt] = f32x4{0.f,0.f,0.f,0.f};
    }
  }
  __syncthreads();

  auto stageKV = [&](int bufi, int kc){
    int j0 = kc<<6;
#pragma unroll
    for (int i=0;i<2;i++){
      int off  = w*2048 + i*1024;
      int loff = off + lane*16;
      int row  = loff>>7, p = (loff&127)>>4;
      async16(qkv + (size_t)(b*NTOK + j0 + row)*3072 + 1024 + hh*64 + ((p^(row&7))<<3),
              (char*)Ks[bufi] + off);
      async16(vT + (size_t)(bh*64 + row)*NTOK + j0 + ((p^(row&7))<<3),
              (char*)Vs[bufi] + off);
    }
  };

  stageKV(0,0);

  for (int kc=0; kc<16; kc++){
    int cur = kc&1;
    int j0 = kc*64;
    if (kc<15) stageKV(cur^1, kc+1);
    if (kc<15) asm volatile("s_waitcnt vmcnt(4)" ::: "memory");
    else       asm volatile("s_waitcnt vmcnt(0)" ::: "memory");
    __builtin_amdgcn_s_barrier();

    float colf[4];
#pragma unroll
    for (int jt=0;jt<4;jt++) colf[jt] = fm[j0 + jt*16 + (lane&15)];

    f32x4 sc[2][4];
    __builtin_amdgcn_s_setprio(1);
#pragma unroll
    for (int jt=0;jt<4;jt++){
      sc[0][jt] = f32x4{0.f,0.f,0.f,0.f};
      sc[1][jt] = f32x4{0.f,0.f,0.f,0.f};
#pragma unroll
      for (int ks=0;ks<2;ks++){
        int row = jt*16 + (lane&15);
        int c = (ks*4 + (lane>>4)) ^ (row&7);
        s16x8 bk = *(const s16x8*)((const char*)Ks[cur] + row*128 + c*16);
        sc[0][jt] = MFMA(aq[0][ks], bk, sc[0][jt]);
        sc[1][jt] = MFMA(aq[1][ks], bk, sc[1][jt]);
      }
    }
    __builtin_amdgcn_s_setprio(0);

#pragma unroll
    for (int s=0;s<2;s++)
#pragma unroll
      for (int jt=0;jt<4;jt++)
#pragma unroll
        for (int r=0;r<4;r++){
          float sv = sc[s][jt][r]*SCALE;
          sc[s][jt][r] = (colf[jt]!=0.f || rowm[s][r]) ? -1000.f : sv;
        }

    // row max + T13 defer-max
    bool need = false;
    float pmax[2][4];
#pragma unroll
    for (int s=0;s<2;s++)
#pragma unroll
      for (int r=0;r<4;r++){
        float mx = fmaxf(fmaxf(sc[s][0][r],sc[s][1][r]), fmaxf(sc[s][2][r],sc[s][3][r]));
#pragma unroll
        for (int ofs=8;ofs>=1;ofs>>=1) mx = fmaxf(mx, __shfl_xor(mx, ofs));
        pmax[s][r] = mx;
        need = need || (mx - mreg[s][r] > 8.f);
      }
    if (__any(need)){
#pragma unroll
      for (int s=0;s<2;s++)
#pragma unroll
        for (int r=0;r<4;r++){
          float mnew  = fmaxf(mreg[s][r], pmax[s][r]);
          float alpha = __expf(mreg[s][r]-mnew);
          mreg[s][r] = mnew;
          lsum[s][r] *= alpha;
#pragma unroll
          for (int nt=0;nt<4;nt++) o[s][nt][r] *= alpha;
        }
    }

    // P = exp(S - m), per-lane partial sums, pack to per-wave LDS
#pragma unroll
    for (int s=0;s<2;s++)
#pragma unroll
      for (int jt=0;jt<4;jt++)
#pragma unroll
        for (int r=0;r<4;r++){
          float p = __expf(sc[s][jt][r]-mreg[s][r]);
          sc[s][jt][r] = p; lsum[s][r] += p;
        }
#pragma unroll
    for (int s=0;s<2;s++)
#pragma unroll
      for (int jt=0;jt<4;jt++)
#pragma unroll
        for (int r=0;r<4;r++){
          int ir = ((lane>>4)<<2)+r, jc = jt*16+(lane&15);
          int byteoff = ir*128 + ((((jc>>3))^(ir&7))<<4) + ((jc&7)<<1);
          *((unsigned short*)((char*)Pb[w][s] + byteoff)) = f2bf(sc[s][jt][r]);
        }

    __builtin_amdgcn_s_setprio(1);
#pragma unroll
    for (int ks=0;ks<2;ks++){
      int rowp = lane&15;
      int cp = (ks*4 + (lane>>4)) ^ (rowp&7);
      s16x8 ap0 = *(const s16x8*)((const char*)Pb[w][0] + rowp*128 + cp*16);
      s16x8 ap1 = *(const s16x8*)((const char*)Pb[w][1] + rowp*128 + cp*16);
#pragma unroll
      for (int nt=0;nt<4;nt++){
        int d = nt*16 + (lane&15);
        int c = (ks*4 + (lane>>4)) ^ (d&7);
        s16x8 bv = *(const s16x8*)((const char*)Vs[cur] + d*128 + c*16);
        o[0][nt] = MFMA(ap0, bv, o[0][nt]);
        o[1][nt] = MFMA(ap1, bv, o[1][nt]);
      }
    }
    __builtin_amdgcn_s_setprio(0);
    __builtin_amdgcn_s_barrier();
  }

#pragma unroll
  for (int s=0;s<2;s++)
#pragma unroll
    for (int r=0;r<4;r++){
      float ls = lsum[s][r];
#pragma unroll
      for (int ofs=8;ofs>=1;ofs>>=1) ls += __shfl_xor(ls, ofs);
      float inv = 1.f/ls;
      int i = qt*128 + s*64 + w*16 + ((lane>>4)<<2) + r;
#pragma unroll
      for (int nt=0;nt<4;nt++){
        int d = nt*16 + (lane&15);
        outb[(size_t)(b*NTOK+i)*DIM + hh*64 + d] = f2bf(o[s][nt][r]*inv);
      }
    }
}

// ---------------------------------------------------------------------------
extern "C" void kernel_launch(void* const* d_in, const int* in_sizes, int n_in,
                              void* d_out, int out_size, void* d_ws, size_t ws_size,
                              hipStream_t stream)
{
  const float* xin0 = (const float*)d_in[0];
  const float* Wqkv = (const float*)d_in[1];
  const float* Wout = (const float*)d_in[2];
  const float* bout = (const float*)d_in[3];
  const float* ln1g = (const float*)d_in[4];
  const float* ln1b = (const float*)d_in[5];
  const float* W1   = (const float*)d_in[6];
  const float* b1   = (const float*)d_in[7];
  const float* W2   = (const float*)d_in[8];
  const float* b2   = (const float*)d_in[9];
  const float* ln2g = (const float*)d_in[10];
  const float* ln2b = (const float*)d_in[11];
  const int*   mnp  = (const int*)d_in[12];
  const int*   mbt  = (const int*)d_in[13];
  float* out = (float*)d_out;

  unsigned short* Wqkv_t = (unsigned short*)d_ws;
  unsigned short* Wout_t = Wqkv_t + (size_t)4*3072*1024;
  unsigned short* W1_t   = Wout_t + (size_t)4*1024*1024;
  unsigned short* W2_t   = W1_t   + (size_t)4*4096*1024;
  float*          x      = (float*)(W2_t + (size_t)4*1024*4096);
  unsigned short* hbuf   = (unsigned short*)(x + (size_t)ROWS*DIM);
  unsigned short* qkvb   = hbuf  + (size_t)ROWS*DIM;
  unsigned short* vTb    = qkvb  + (size_t)ROWS*3072;
  unsigned short* attnb  = vTb   + (size_t)ROWS*DIM;
  unsigned short* gbuf   = attnb + (size_t)ROWS*DIM;
  // MLP2 split-K partials overlay hbuf+qkvb (dead during MLP2): 4*ROWS*DIM bf16
  unsigned short* pbuf   = hbuf;

  wt_kernel<<<dim3(3072/64,1024/64,4),256,0,stream>>>(Wqkv, Wqkv_t, 1024, 3072);
  wt_kernel<<<dim3(1024/64,1024/64,4),256,0,stream>>>(Wout, Wout_t, 1024, 1024);
  wt_kernel<<<dim3(4096/64,1024/64,4),256,0,stream>>>(W1,   W1_t,   1024, 4096);
  wt_kernel<<<dim3(1024/64,4096/64,4),256,0,stream>>>(W2,   W2_t,   4096, 1024);

  for (int l=0;l<4;l++){
    const float* xres = (l==0) ? xin0 : x;
    ln_kernel<<<1024,256,0,stream>>>(xres, ln1g+l*DIM, ln1b+l*DIM, hbuf);
    gemm_tb_kernel<0><<<192,512,0,stream>>>(hbuf, Wqkv_t + (size_t)l*3072*1024,
        qkvb, nullptr, ROWS, 3072, 1024, 1024, 3072, 1, 0);
    vtrans_kernel<<<dim3(16,64),256,0,stream>>>(qkvb, vTb);
    attn_kernel<<<dim3(8,64),256,0,stream>>>(qkvb, vTb, mnp, mbt, attnb);
    gemm_kernel<64,1><<<512,256,0,stream>>>(attnb, Wout_t + (size_t)l*1024*1024,
        nullptr, x, xres, bout+l*DIM, ROWS, 1024, 1024, 1024);
    ln_kernel<<<1024,256,0,stream>>>(x, ln2g+l*DIM, ln2b+l*DIM, hbuf);
    gemm_tb_kernel<2><<<256,512,0,stream>>>(hbuf, W1_t + (size_t)l*4096*1024,
        gbuf, b1+l*MLPD, ROWS, 4096, 1024, 1024, 4096, 1, 0);
    // MLP2 split-K=4 into bf16 partials (overlaying dead hbuf/qkvb), then combine
    gemm_tb_kernel<0><<<256,512,0,stream>>>(gbuf, W2_t + (size_t)l*1024*4096,
        pbuf, nullptr, ROWS, 1024, 1024, 4096, 1024, 4, (size_t)ROWS*DIM);
    float* xo = (l==3) ? out : x;
    mlp2add_kernel<<<ROWS*DIM/1024,256,0,stream>>>(pbuf, x, b2+l*DIM, xo);
  }
}

// Round 4
// 1171.890 us; speedup vs baseline: 1.0737x; 1.0184x over previous
//
#include <hip/hip_runtime.h>
#include <hip/hip_bf16.h>

#define DEPTH 4
#define HEADS 16
#define DIMH  64
#define DIM   1024
#define MLPD  4096
#define NTOK  1024
#define BATCH 4
#define ROWS  (BATCH*NTOK)      // 4096
#define SCALE 0.125f            // 64^-0.5

typedef float f32x4 __attribute__((ext_vector_type(4)));
typedef short s16x8 __attribute__((ext_vector_type(8)));

#define MFMA(a,b,c) __builtin_amdgcn_mfma_f32_16x16x32_bf16((a),(b),(c),0,0,0)

__device__ __forceinline__ unsigned short f2bf(float f){
  union{ __hip_bfloat16 h; unsigned short u; } x; x.h = __float2bfloat16(f); return x.u;
}
__device__ __forceinline__ float bf2f(unsigned short u){
  return __uint_as_float(((unsigned)u)<<16);
}

__device__ __forceinline__ void async16(const void* g, void* l){
  __builtin_amdgcn_global_load_lds(
      (const __attribute__((address_space(1))) void*)g,
      (__attribute__((address_space(3))) void*)l, 16, 0, 0);
}

// ---------------------------------------------------------------------------
// Weight convert+transpose: src fp32 [D][K][N] -> dst bf16(ushort) [D][N][K]
// ---------------------------------------------------------------------------
__global__ __launch_bounds__(256) void wt_kernel(const float* __restrict__ src,
    unsigned short* __restrict__ dst, int K, int N)
{
  __shared__ float t[64][65];
  int n0 = blockIdx.x*64, k0 = blockIdx.y*64;
  src += (size_t)blockIdx.z*K*N;
  dst += (size_t)blockIdx.z*N*K;
  int tid = threadIdx.x;
  int r = tid>>4, c4 = (tid&15)*4;
#pragma unroll
  for (int p=0;p<4;p++){
    int row = r + p*16;
    float4 v = *(const float4*)(src + (size_t)(k0+row)*N + n0 + c4);
    t[c4+0][row]=v.x; t[c4+1][row]=v.y; t[c4+2][row]=v.z; t[c4+3][row]=v.w;
  }
  __syncthreads();
  int rn = tid>>2, ch = tid&3;
  unsigned short o[16];
#pragma unroll
  for (int i=0;i<16;i++) o[i] = f2bf(t[rn][ch*16+i]);
  uint4* d = (uint4*)(dst + (size_t)(n0+rn)*K + k0 + ch*16);
  d[0] = ((uint4*)o)[0]; d[1] = ((uint4*)o)[1];
}

// ---------------------------------------------------------------------------
// LayerNorm fp32 -> bf16. One wave per row.
// ---------------------------------------------------------------------------
__global__ __launch_bounds__(256) void ln_kernel(const float* __restrict__ x,
    const float* __restrict__ g, const float* __restrict__ b,
    unsigned short* __restrict__ h)
{
  int row  = blockIdx.x*4 + (threadIdx.x>>6);
  int lane = threadIdx.x & 63;
  const float* xr = x + (size_t)row*DIM;
  float4 v[4]; float s=0.f, ss=0.f;
#pragma unroll
  for (int c=0;c<4;c++){
    v[c] = *(const float4*)(xr + c*256 + lane*4);
    s  += v[c].x+v[c].y+v[c].z+v[c].w;
    ss += v[c].x*v[c].x+v[c].y*v[c].y+v[c].z*v[c].z+v[c].w*v[c].w;
  }
#pragma unroll
  for (int o=1;o<64;o<<=1){ s += __shfl_xor(s,o); ss += __shfl_xor(ss,o); }
  float mu  = s*(1.f/1024.f);
  float var = ss*(1.f/1024.f) - mu*mu;
  float rstd = rsqrtf(var + 1e-5f);
#pragma unroll
  for (int c=0;c<4;c++){
    float4 gg = *(const float4*)(g + c*256 + lane*4);
    float4 bb = *(const float4*)(b + c*256 + lane*4);
    ushort4 o;
    o.x = f2bf((v[c].x-mu)*rstd*gg.x + bb.x);
    o.y = f2bf((v[c].y-mu)*rstd*gg.y + bb.y);
    o.z = f2bf((v[c].z-mu)*rstd*gg.z + bb.z);
    o.w = f2bf((v[c].w-mu)*rstd*gg.w + bb.w);
    *(ushort4*)(h + (size_t)row*DIM + c*256 + lane*4) = o;
  }
}

// ---------------------------------------------------------------------------
// V transpose: qkv bf16 [B*N][3072] (v cols 2048..3071) -> vT [B*H*64][N]
// ---------------------------------------------------------------------------
__global__ __launch_bounds__(256) void vtrans_kernel(
    const unsigned short* __restrict__ qkv, unsigned short* __restrict__ vT)
{
  __shared__ float t[64][65];
  int n0 = blockIdx.x*64;
  int bh = blockIdx.y; int b = bh>>4, hh = bh&15;
  int tid = threadIdx.x;
  int r = tid>>4, c4 = (tid&15)*4;
#pragma unroll
  for (int p=0;p<4;p++){
    int row = r + p*16;
    ushort4 u = *(const ushort4*)(qkv + (size_t)(b*NTOK + n0 + row)*3072 + 2048 + hh*64 + c4);
    t[c4+0][row]=bf2f(u.x); t[c4+1][row]=bf2f(u.y); t[c4+2][row]=bf2f(u.z); t[c4+3][row]=bf2f(u.w);
  }
  __syncthreads();
  int rn = tid>>2, ch = tid&3;
  unsigned short o[16];
#pragma unroll
  for (int i=0;i<16;i++) o[i] = f2bf(t[rn][ch*16+i]);
  uint4* d = (uint4*)(vT + (size_t)(bh*64 + rn)*NTOK + n0 + ch*16);
  d[0] = ((uint4*)o)[0]; d[1] = ((uint4*)o)[1];
}

// ---------------------------------------------------------------------------
// 128x64 m97-structure GEMM, kept for Wout (N=1024, fused res+bias fp32 out).
// ---------------------------------------------------------------------------
template<int BN, int EPI>
__global__ __launch_bounds__(256) void gemm_kernel(
    const unsigned short* __restrict__ A,
    const unsigned short* __restrict__ Bt,
    unsigned short* __restrict__ outb,
    float* __restrict__ outf,
    const float* __restrict__ res,
    const float* __restrict__ bias,
    int M, int N, int K, int ldout)
{
  constexpr int BM=128, BK=64;
  constexpr int NT = BN/32;
  __shared__ unsigned short As[BM*BK];
  __shared__ unsigned short Bs[BN*BK];
  int tid = threadIdx.x, lane = tid&63, w = tid>>6;
  int wm = w&1, wn = w>>1;

  int gn  = N/BN;
  int nwg = (M/BM)*gn;
  int bid = blockIdx.x;
  int id  = (nwg%8==0) ? ((bid&7)*(nwg>>3) + (bid>>3)) : bid;
  int m0 = (id/gn)*BM, n0 = (id%gn)*BN;

  f32x4 acc[4][NT] = {};

  for (int k0=0; k0<K; k0+=BK){
    __syncthreads();
#pragma unroll
    for (int i=0;i<4;i++){
      int off = w*4096 + i*1024 + lane*16;
      int row = off>>7, p = (off&127)>>4;
      async16(A + (size_t)(m0+row)*K + k0 + ((p^(row&7))<<3),
              (char*)As + w*4096 + i*1024);
    }
#pragma unroll
    for (int i=0;i<NT;i++){
      int off = w*(BN*32) + i*1024 + lane*16;
      int row = off>>7, p = (off&127)>>4;
      async16(Bt + (size_t)(n0+row)*K + k0 + ((p^(row&7))<<3),
              (char*)Bs + w*(BN*32) + i*1024);
    }
    __syncthreads();
#pragma unroll
    for (int ks=0;ks<2;ks++){
      s16x8 a[4], bfr[NT];
#pragma unroll
      for (int mt=0;mt<4;mt++){
        int row = wm*64 + mt*16 + (lane&15);
        int c = (ks*4 + (lane>>4)) ^ (row&7);
        a[mt] = *(const s16x8*)((const char*)As + row*128 + c*16);
      }
#pragma unroll
      for (int nt=0;nt<NT;nt++){
        int row = wn*(BN/2) + nt*16 + (lane&15);
        int c = (ks*4 + (lane>>4)) ^ (row&7);
        bfr[nt] = *(const s16x8*)((const char*)Bs + row*128 + c*16);
      }
#pragma unroll
      for (int mt=0;mt<4;mt++)
#pragma unroll
        for (int nt=0;nt<NT;nt++)
          acc[mt][nt] = MFMA(a[mt], bfr[nt], acc[mt][nt]);
    }
  }

#pragma unroll
  for (int mt=0;mt<4;mt++)
#pragma unroll
    for (int nt=0;nt<NT;nt++)
#pragma unroll
      for (int r=0;r<4;r++){
        int row = m0 + wm*64 + mt*16 + ((lane>>4)<<2) + r;
        int col = n0 + wn*(BN/2) + nt*16 + (lane&15);
        float v = acc[mt][nt][r];
        if (EPI==0){
          outb[(size_t)row*ldout + col] = f2bf(v);
        } else if (EPI==1){
          float t = v + res[(size_t)row*ldout + col] + bias[col];
          outf[(size_t)row*ldout + col] = t;
        } else {
          float t = v + bias[col];
          t = 0.5f*t*(1.f + erff(t*0.70710678118f));
          outb[(size_t)row*ldout + col] = f2bf(t);
        }
      }
}

// ---------------------------------------------------------------------------
// 256x256 BK=32 triple-buffered GEMM, 512 thr = 8 waves (2M x 4N), wave tile
// 128x64. LDS 96KB = 3 bufs x (A 16KB + B 16KB). 64B rows with chunk-XOR
// swizzle: physical 16B chunk p = logical c ^ ((row>>1)&3). Write side keeps
// the LDS dest linear (global_load_lds) and pre-swizzles the per-lane global
// source (rule #21); read side applies the same XOR -> every bank hit exactly
// 8x per wave64 ds_read_b128 = conflict-free.
// Schedule per K-step t: stage T(t+2) into buf (t+2)%3 (WAR sealed by iter
// t-1's end barrier), ds_read buf t%3, 32 MFMA, vmcnt(4) retires T(t+1),
// barrier. EPI 0: bf16 store (+split-K slabs). EPI 2: bias+gelu bf16.
// ---------------------------------------------------------------------------
template<int EPI>
__global__ __launch_bounds__(512,2) void gemm_tb_kernel(
    const unsigned short* __restrict__ A,   // [M][lda]
    const unsigned short* __restrict__ Bt,  // [N][lda]
    unsigned short* __restrict__ outb,
    const float* __restrict__ bias,
    int M, int N, int K, int lda, int ldout, int SK, size_t oslab)
{
  __shared__ unsigned short lds[3][2][256*32];
  const int tid = threadIdx.x, lane = tid&63, w = tid>>6;
  const int wm = w>>2, wn = w&3;
  const int gn = N>>8;
  const int ntile = (M>>8)*gn;
  const int nwg = ntile*SK;
  int id;
  { const int q = nwg>>3, r = nwg&7, xc = blockIdx.x&7, od = blockIdx.x>>3;
    id = (xc<r ? xc*(q+1) : r*(q+1)+(xc-r)*q) + od; }
  const int sk = id/ntile, tt = id%ntile;
  const int m0 = (tt/gn)<<8, n0 = (tt%gn)<<8;
  const int kbase = sk*K;
  unsigned short* outp = outb + (size_t)sk*oslab;
  const int nkt = K>>5;

  f32x4 acc[8][4] = {};

  auto stage = [&](int bsel, int kt){
    const int k0 = kbase + (kt<<5);
#pragma unroll
    for (int i=0;i<2;i++){
      int off  = ((w<<1)+i)<<10;
      int loff = off + lane*16;
      int row  = loff>>6, cl = (loff&63)>>4;
      int cg   = cl ^ ((row>>1)&3);           // pre-swizzled global chunk
      async16(A + (size_t)(m0+row)*lda + k0 + (cg<<3),
              (char*)lds[bsel][0] + off);
    }
#pragma unroll
    for (int i=0;i<2;i++){
      int off  = ((w<<1)+i)<<10;
      int loff = off + lane*16;
      int row  = loff>>6, cl = (loff&63)>>4;
      int cg   = cl ^ ((row>>1)&3);
      async16(Bt + (size_t)(n0+row)*lda + k0 + (cg<<3),
              (char*)lds[bsel][1] + off);
    }
  };

  stage(0,0); stage(1,1);
  asm volatile("s_waitcnt vmcnt(4)" ::: "memory");
  __builtin_amdgcn_s_barrier();

  int cb = 0;
  for (int t=0; t<nkt; ++t){
    int sb = cb+2; if (sb>=3) sb -= 3;
    if (t+2<nkt) stage(sb, t+2);
    s16x8 af[8], bf[4];
#pragma unroll
    for (int mt=0;mt<8;mt++){
      int rw = (wm<<7) + (mt<<4) + (lane&15);
      int ph = (lane>>4) ^ ((rw>>1)&3);
      af[mt] = *(const s16x8*)((const char*)lds[cb][0] + rw*64 + (ph<<4));
    }
#pragma unroll
    for (int nt=0;nt<4;nt++){
      int rw = (wn<<6) + (nt<<4) + (lane&15);
      int ph = (lane>>4) ^ ((rw>>1)&3);
      bf[nt] = *(const s16x8*)((const char*)lds[cb][1] + rw*64 + (ph<<4));
    }
    __builtin_amdgcn_s_setprio(1);
#pragma unroll
    for (int mt=0;mt<8;mt++)
#pragma unroll
      for (int nt=0;nt<4;nt++)
        acc[mt][nt] = MFMA(af[mt], bf[nt], acc[mt][nt]);
    __builtin_amdgcn_s_setprio(0);
    if (t+2<nkt) asm volatile("s_waitcnt vmcnt(4)" ::: "memory");
    else         asm volatile("s_waitcnt vmcnt(0)" ::: "memory");
    __builtin_amdgcn_s_barrier();
    cb = cb+1; if (cb>=3) cb = 0;
  }

#pragma unroll
  for (int mt=0;mt<8;mt++)
#pragma unroll
    for (int nt=0;nt<4;nt++)
#pragma unroll
      for (int rr=0;rr<4;rr++){
        int row = m0 + (wm<<7) + (mt<<4) + ((lane>>4)<<2) + rr;
        int col = n0 + (wn<<6) + (nt<<4) + (lane&15);
        float v = acc[mt][nt][rr];
        if (EPI==2){
          v += bias[col];
          v = 0.5f*v*(1.f + erff(v*0.70710678118f));
        }
        outp[(size_t)row*ldout + col] = f2bf(v);
      }
}

// ---------------------------------------------------------------------------
// MLP2 split-K combine: out = x + b2 + sum of 4 bf16 partial planes.
// ---------------------------------------------------------------------------
__global__ __launch_bounds__(256) void mlp2add_kernel(
    const unsigned short* __restrict__ p, const float* __restrict__ x,
    const float* __restrict__ b2, float* __restrict__ out)
{
  int idx = blockIdx.x*256 + threadIdx.x;
  int i4 = idx<<2;
  int col = i4 & (DIM-1);
  float4 v = *(const float4*)(x + i4);
  float4 bb = *(const float4*)(b2 + col);
  v.x+=bb.x; v.y+=bb.y; v.z+=bb.z; v.w+=bb.w;
#pragma unroll
  for (int s=0;s<4;s++){
    ushort4 u = *(const ushort4*)(p + (size_t)s*ROWS*DIM + i4);
    v.x += bf2f(u.x); v.y += bf2f(u.y); v.z += bf2f(u.z); v.w += bf2f(u.w);
  }
  *(float4*)(out + i4) = v;
}

// ---------------------------------------------------------------------------
// Flash attention. QBLK=128 (4 waves x 2 strips x 16 q-rows), KVBLK=64,
// double-buffered K/V via global_load_lds + counted vmcnt, T13 defer-max,
// per-lane partial row-sums reduced once at the end.
// ---------------------------------------------------------------------------
__global__ __launch_bounds__(256) void attn_kernel(
    const unsigned short* __restrict__ qkv,   // [B*N][3072]
    const unsigned short* __restrict__ vT,    // [B*H*64][N]
    const int* __restrict__ mnp, const int* __restrict__ mbert,
    unsigned short* __restrict__ outb)        // [B*N][1024]
{
  __shared__ unsigned short Ks[2][64*64];
  __shared__ unsigned short Vs[2][64*64];
  __shared__ unsigned short Pb[4][2][16*64];
  __shared__ float fm[NTOK];
  int qt = blockIdx.x, bh = blockIdx.y;
  int b = bh>>4, hh = bh&15;
  int tid = threadIdx.x, lane = tid&63, w = tid>>6;

  for (int j = tid; j < NTOK; j += 256)
    fm[j] = (mnp[b*NTOK+j]==0 || mbert[b*NTOK+j]==1) ? 1.f : 0.f;

  s16x8 aq[2][2];
  bool rowm[2][4]; float mreg[2][4], lsum[2][4]; f32x4 o[2][4];
#pragma unroll
  for (int s=0;s<2;s++){
    int iA = qt*128 + s*64 + w*16 + (lane&15);
#pragma unroll
    for (int ks=0;ks<2;ks++)
      aq[s][ks] = *(const s16x8*)(qkv + (size_t)(b*NTOK+iA)*3072 + hh*64 + ks*32 + ((lane>>4)<<3));
#pragma unroll
    for (int nt=0;nt<4;nt++){
      int i = qt*128 + s*64 + w*16 + ((lane>>4)<<2) + nt;
      rowm[s][nt] = (mnp[b*NTOK+i]==0);
      mreg[s][nt] = -1e30f; lsum[s][nt] = 0.f;
      o[s][nt] = f32x4{0.f,0.f,0.f,0.f};
    }
  }
  __syncthreads();

  auto stageKV = [&](int bufi, int kc){
    int j0 = kc<<6;
#pragma unroll
    for (int i=0;i<2;i++){
      int off  = w*2048 + i*1024;
      int loff = off + lane*16;
      int row  = loff>>7, p = (loff&127)>>4;
      async16(qkv + (size_t)(b*NTOK + j0 + row)*3072 + 1024 + hh*64 + ((p^(row&7))<<3),
              (char*)Ks[bufi] + off);
      async16(vT + (size_t)(bh*64 + row)*NTOK + j0 + ((p^(row&7))<<3),
              (char*)Vs[bufi] + off);
    }
  };

  stageKV(0,0);

  for (int kc=0; kc<16; kc++){
    int cur = kc&1;
    int j0 = kc*64;
    if (kc<15) stageKV(cur^1, kc+1);
    if (kc<15) asm volatile("s_waitcnt vmcnt(4)" ::: "memory");
    else       asm volatile("s_waitcnt vmcnt(0)" ::: "memory");
    __builtin_amdgcn_s_barrier();

    float colf[4];
#pragma unroll
    for (int jt=0;jt<4;jt++) colf[jt] = fm[j0 + jt*16 + (lane&15)];

    f32x4 sc[2][4];
    __builtin_amdgcn_s_setprio(1);
#pragma unroll
    for (int jt=0;jt<4;jt++){
      sc[0][jt] = f32x4{0.f,0.f,0.f,0.f};
      sc[1][jt] = f32x4{0.f,0.f,0.f,0.f};
#pragma unroll
      for (int ks=0;ks<2;ks++){
        int row = jt*16 + (lane&15);
        int c = (ks*4 + (lane>>4)) ^ (row&7);
        s16x8 bk = *(const s16x8*)((const char*)Ks[cur] + row*128 + c*16);
        sc[0][jt] = MFMA(aq[0][ks], bk, sc[0][jt]);
        sc[1][jt] = MFMA(aq[1][ks], bk, sc[1][jt]);
      }
    }
    __builtin_amdgcn_s_setprio(0);

#pragma unroll
    for (int s=0;s<2;s++)
#pragma unroll
      for (int jt=0;jt<4;jt++)
#pragma unroll
        for (int r=0;r<4;r++){
          float sv = sc[s][jt][r]*SCALE;
          sc[s][jt][r] = (colf[jt]!=0.f || rowm[s][r]) ? -1000.f : sv;
        }

    // row max + T13 defer-max
    bool need = false;
    float pmax[2][4];
#pragma unroll
    for (int s=0;s<2;s++)
#pragma unroll
      for (int r=0;r<4;r++){
        float mx = fmaxf(fmaxf(sc[s][0][r],sc[s][1][r]), fmaxf(sc[s][2][r],sc[s][3][r]));
#pragma unroll
        for (int ofs=8;ofs>=1;ofs>>=1) mx = fmaxf(mx, __shfl_xor(mx, ofs));
        pmax[s][r] = mx;
        need = need || (mx - mreg[s][r] > 8.f);
      }
    if (__any(need)){
#pragma unroll
      for (int s=0;s<2;s++)
#pragma unroll
        for (int r=0;r<4;r++){
          float mnew  = fmaxf(mreg[s][r], pmax[s][r]);
          float alpha = __expf(mreg[s][r]-mnew);
          mreg[s][r] = mnew;
          lsum[s][r] *= alpha;
#pragma unroll
          for (int nt=0;nt<4;nt++) o[s][nt][r] *= alpha;
        }
    }

    // P = exp(S - m), per-lane partial sums, pack to per-wave LDS
#pragma unroll
    for (int s=0;s<2;s++)
#pragma unroll
      for (int jt=0;jt<4;jt++)
#pragma unroll
        for (int r=0;r<4;r++){
          float p = __expf(sc[s][jt][r]-mreg[s][r]);
          sc[s][jt][r] = p; lsum[s][r] += p;
        }
#pragma unroll
    for (int s=0;s<2;s++)
#pragma unroll
      for (int jt=0;jt<4;jt++)
#pragma unroll
        for (int r=0;r<4;r++){
          int ir = ((lane>>4)<<2)+r, jc = jt*16+(lane&15);
          int byteoff = ir*128 + ((((jc>>3))^(ir&7))<<4) + ((jc&7)<<1);
          *((unsigned short*)((char*)Pb[w][s] + byteoff)) = f2bf(sc[s][jt][r]);
        }

    __builtin_amdgcn_s_setprio(1);
#pragma unroll
    for (int ks=0;ks<2;ks++){
      int rowp = lane&15;
      int cp = (ks*4 + (lane>>4)) ^ (rowp&7);
      s16x8 ap0 = *(const s16x8*)((const char*)Pb[w][0] + rowp*128 + cp*16);
      s16x8 ap1 = *(const s16x8*)((const char*)Pb[w][1] + rowp*128 + cp*16);
#pragma unroll
      for (int nt=0;nt<4;nt++){
        int d = nt*16 + (lane&15);
        int c = (ks*4 + (lane>>4)) ^ (d&7);
        s16x8 bv = *(const s16x8*)((const char*)Vs[cur] + d*128 + c*16);
        o[0][nt] = MFMA(ap0, bv, o[0][nt]);
        o[1][nt] = MFMA(ap1, bv, o[1][nt]);
      }
    }
    __builtin_amdgcn_s_setprio(0);
    __builtin_amdgcn_s_barrier();
  }

#pragma unroll
  for (int s=0;s<2;s++)
#pragma unroll
    for (int r=0;r<4;r++){
      float ls = lsum[s][r];
#pragma unroll
      for (int ofs=8;ofs>=1;ofs>>=1) ls += __shfl_xor(ls, ofs);
      float inv = 1.f/ls;
      int i = qt*128 + s*64 + w*16 + ((lane>>4)<<2) + r;
#pragma unroll
      for (int nt=0;nt<4;nt++){
        int d = nt*16 + (lane&15);
        outb[(size_t)(b*NTOK+i)*DIM + hh*64 + d] = f2bf(o[s][nt][r]*inv);
      }
    }
}

// ---------------------------------------------------------------------------
extern "C" void kernel_launch(void* const* d_in, const int* in_sizes, int n_in,
                              void* d_out, int out_size, void* d_ws, size_t ws_size,
                              hipStream_t stream)
{
  const float* xin0 = (const float*)d_in[0];
  const float* Wqkv = (const float*)d_in[1];
  const float* Wout = (const float*)d_in[2];
  const float* bout = (const float*)d_in[3];
  const float* ln1g = (const float*)d_in[4];
  const float* ln1b = (const float*)d_in[5];
  const float* W1   = (const float*)d_in[6];
  const float* b1   = (const float*)d_in[7];
  const float* W2   = (const float*)d_in[8];
  const float* b2   = (const float*)d_in[9];
  const float* ln2g = (const float*)d_in[10];
  const float* ln2b = (const float*)d_in[11];
  const int*   mnp  = (const int*)d_in[12];
  const int*   mbt  = (const int*)d_in[13];
  float* out = (float*)d_out;

  unsigned short* Wqkv_t = (unsigned short*)d_ws;
  unsigned short* Wout_t = Wqkv_t + (size_t)4*3072*1024;
  unsigned short* W1_t   = Wout_t + (size_t)4*1024*1024;
  unsigned short* W2_t   = W1_t   + (size_t)4*4096*1024;
  float*          x      = (float*)(W2_t + (size_t)4*1024*4096);
  unsigned short* hbuf   = (unsigned short*)(x + (size_t)ROWS*DIM);
  unsigned short* qkvb   = hbuf  + (size_t)ROWS*DIM;
  unsigned short* vTb    = qkvb  + (size_t)ROWS*3072;
  unsigned short* attnb  = vTb   + (size_t)ROWS*DIM;
  unsigned short* gbuf   = attnb + (size_t)ROWS*DIM;
  // MLP2 split-K partials overlay hbuf+qkvb (dead during MLP2): 4*ROWS*DIM bf16
  unsigned short* pbuf   = hbuf;

  wt_kernel<<<dim3(3072/64,1024/64,4),256,0,stream>>>(Wqkv, Wqkv_t, 1024, 3072);
  wt_kernel<<<dim3(1024/64,1024/64,4),256,0,stream>>>(Wout, Wout_t, 1024, 1024);
  wt_kernel<<<dim3(4096/64,1024/64,4),256,0,stream>>>(W1,   W1_t,   1024, 4096);
  wt_kernel<<<dim3(1024/64,4096/64,4),256,0,stream>>>(W2,   W2_t,   4096, 1024);

  for (int l=0;l<4;l++){
    const float* xres = (l==0) ? xin0 : x;
    ln_kernel<<<1024,256,0,stream>>>(xres, ln1g+l*DIM, ln1b+l*DIM, hbuf);
    gemm_tb_kernel<0><<<192,512,0,stream>>>(hbuf, Wqkv_t + (size_t)l*3072*1024,
        qkvb, nullptr, ROWS, 3072, 1024, 1024, 3072, 1, 0);
    vtrans_kernel<<<dim3(16,64),256,0,stream>>>(qkvb, vTb);
    attn_kernel<<<dim3(8,64),256,0,stream>>>(qkvb, vTb, mnp, mbt, attnb);
    gemm_kernel<64,1><<<512,256,0,stream>>>(attnb, Wout_t + (size_t)l*1024*1024,
        nullptr, x, xres, bout+l*DIM, ROWS, 1024, 1024, 1024);
    ln_kernel<<<1024,256,0,stream>>>(x, ln2g+l*DIM, ln2b+l*DIM, hbuf);
    gemm_tb_kernel<2><<<256,512,0,stream>>>(hbuf, W1_t + (size_t)l*4096*1024,
        gbuf, b1+l*MLPD, ROWS, 4096, 1024, 1024, 4096, 1, 0);
    // MLP2 split-K=4 into bf16 partials (overlaying dead hbuf/qkvb), then combine
    gemm_tb_kernel<0><<<256,512,0,stream>>>(gbuf, W2_t + (size_t)l*1024*4096,
        pbuf, nullptr, ROWS, 1024, 1024, 4096, 1024, 4, (size_t)ROWS*DIM);
    float* xo = (l==3) ? out : x;
    mlp2add_kernel<<<ROWS*DIM/1024,256,0,stream>>>(pbuf, x, b2+l*DIM, xo);
  }
}